// Round 1
// baseline (354.460 us; speedup 1.0000x reference)
//
#include <hip/hip_runtime.h>
#include <cstdint>
#include <cstddef>

#define TOKENS 16384
#define DIM    2048
#define NEXP   8
#define RANK   128
#define NOUT   2048

typedef __attribute__((ext_vector_type(4))) float    f32x4;
typedef __attribute__((ext_vector_type(8))) _Float16 f16x8;
typedef __attribute__((ext_vector_type(4))) _Float16 f16x4;

// ---------------------------------------------------------------- utilities
__device__ __forceinline__ void gload_lds16(const void* g, void* l) {
  __builtin_amdgcn_global_load_lds(
      (const __attribute__((address_space(1))) void*)g,
      (__attribute__((address_space(3))) void*)l, 16, 0, 0);
}

// ------------------------------------------------- transpose + cast to f16
// in: [E][R][C] fp32.  out element: out[e*obase + c*ostride + r] = in[e][r][c]
__global__ __launch_bounds__(256) void transpose_cast_f16(
    const float* __restrict__ in, _Float16* __restrict__ out,
    int R, int C, long ostride, long obase)
{
  __shared__ float tile[32][33];
  const int e = blockIdx.z;
  const float* ine = in + (size_t)e * R * C;
  const int c0 = blockIdx.x * 32, r0 = blockIdx.y * 32;
  const int tx = threadIdx.x, ty = threadIdx.y;
#pragma unroll
  for (int j = 0; j < 32; j += 8)
    tile[ty + j][tx] = ine[(size_t)(r0 + ty + j) * C + (c0 + tx)];
  __syncthreads();
#pragma unroll
  for (int j = 0; j < 32; j += 8)
    out[(size_t)e * obase + (size_t)(c0 + ty + j) * ostride + (r0 + tx)] =
        (_Float16)tile[tx][ty + j];
}

// ------------------------------------------------------------------ router
// 16 tokens per block, 16 lanes per token (128 features each).
// Produces combine[T][8] (normalized top-2 softmax weights, zeros elsewhere)
// and xh = f16(x).
__global__ __launch_bounds__(256) void router_kernel(
    const float* __restrict__ x, const float* __restrict__ rw,
    float* __restrict__ combine, _Float16* __restrict__ xh)
{
  const int tid = threadIdx.x;
  const int tok = tid >> 4;
  const int fs  = tid & 15;
  const size_t t = (size_t)blockIdx.x * 16 + tok;
  const float*  xr  = x  + t * DIM + fs * 128;
  _Float16*     xhr = xh + t * DIM + fs * 128;
  const float*  rwb = rw + (size_t)fs * 128 * NEXP;

  float ss = 0.f;
  float lg[8];
#pragma unroll
  for (int e = 0; e < 8; ++e) lg[e] = 0.f;

#pragma unroll 2
  for (int c = 0; c < 128; c += 4) {
    float4 v = *(const float4*)(xr + c);
    f16x4 hv;
    hv.x = (_Float16)v.x; hv.y = (_Float16)v.y;
    hv.z = (_Float16)v.z; hv.w = (_Float16)v.w;
    *(f16x4*)(xhr + c) = hv;
    const float* rp = rwb + c * 8;
    float xs[4] = {v.x, v.y, v.z, v.w};
#pragma unroll
    for (int j = 0; j < 4; ++j) {
      const float xv = xs[j];
      ss = fmaf(xv, xv, ss);
      float4 r0 = *(const float4*)(rp + j * 8);
      float4 r1 = *(const float4*)(rp + j * 8 + 4);
      lg[0] = fmaf(xv, r0.x, lg[0]); lg[1] = fmaf(xv, r0.y, lg[1]);
      lg[2] = fmaf(xv, r0.z, lg[2]); lg[3] = fmaf(xv, r0.w, lg[3]);
      lg[4] = fmaf(xv, r1.x, lg[4]); lg[5] = fmaf(xv, r1.y, lg[5]);
      lg[6] = fmaf(xv, r1.z, lg[6]); lg[7] = fmaf(xv, r1.w, lg[7]);
    }
  }
  // reduce across the 16 lanes of this token
#pragma unroll
  for (int m = 1; m < 16; m <<= 1) {
    ss += __shfl_xor(ss, m, 64);
#pragma unroll
    for (int e = 0; e < 8; ++e) lg[e] += __shfl_xor(lg[e], m, 64);
  }
  if (fs == 0) {
    const float inv = 1.f / fmaxf(sqrtf(ss), 1e-12f);
#pragma unroll
    for (int e = 0; e < 8; ++e) lg[e] *= inv;
    // top-2 (static register indexing only)
    float b1 = lg[0]; int e1 = 0;
#pragma unroll
    for (int e = 1; e < 8; ++e)
      if (lg[e] > b1) { b1 = lg[e]; e1 = e; }
    float b2 = -3.4e38f; int e2 = 0;
#pragma unroll
    for (int e = 0; e < 8; ++e)
      if (e != e1 && lg[e] > b2) { b2 = lg[e]; e2 = e; }
    const float p2 = expf(b2 - b1);          // softmax top-2, renormalized
    const float w1 = 1.f / (1.f + p2);
    const float w2 = p2 * w1;
    float ov[8];
#pragma unroll
    for (int e = 0; e < 8; ++e)
      ov[e] = (e == e1) ? w1 : ((e == e2) ? w2 : 0.f);
    float4* cp = (float4*)(combine + t * 8);
    cp[0] = make_float4(ov[0], ov[1], ov[2], ov[3]);
    cp[1] = make_float4(ov[4], ov[5], ov[6], ov[7]);
  }
}

// -------------------------------------------------------------------- GEMM
// C[M][ldc] = A[M][KDIM] @ Bt[N][KDIM]^T, 128x128 tile, BK=64, 4 waves.
// global_load_lds(16B) with pre-swizzled source; XOR-swizzled ds_read_b128;
// 16x16x32 f16 MFMA. SCALED: C is f16, scaled by combine[row*8 + n0>>7].
template <int KDIM, bool SCALED>
__global__ __launch_bounds__(256) void gemm_bt(
    const _Float16* __restrict__ A, const _Float16* __restrict__ Bt,
    const float* __restrict__ combine, void* __restrict__ Cout, int ldc)
{
  __shared__ __align__(16) char lds[32768];
  char* ldsA = lds;
  char* ldsB = lds + 16384;
  const int tid = threadIdx.x;
  const int w = tid >> 6, l = tid & 63;
  const int wm = w >> 1, wn = w & 1;
  const size_t m0 = (size_t)blockIdx.y * 128;
  const size_t n0 = (size_t)blockIdx.x * 128;

  // staging: linear LDS dest, inverse-swizzled global source (rule #21)
  const int Lb = w * 1024 + l * 16;
  const _Float16* agp[4];
  const _Float16* bgp[4];
  int ldst[4];
#pragma unroll
  for (int i = 0; i < 4; ++i) {
    const int L = i * 4096 + Lb;
    const int row = L >> 7;                       // tile row (128B rows)
    const int cb = (L & 127) ^ ((row & 7) << 4);  // swizzled column byte
    agp[i] = A  + (m0 + row) * KDIM + (cb >> 1);
    bgp[i] = Bt + (n0 + row) * KDIM + (cb >> 1);
    ldst[i] = i * 4096 + w * 1024;                // wave-uniform LDS base
  }

  f32x4 acc[4][4];
#pragma unroll
  for (int a = 0; a < 4; ++a)
#pragma unroll
    for (int b = 0; b < 4; ++b)
#pragma unroll
      for (int j = 0; j < 4; ++j) acc[a][b][j] = 0.f;

  for (int kt = 0; kt < KDIM; kt += 64) {
#pragma unroll
    for (int i = 0; i < 4; ++i) {
      gload_lds16(agp[i] + kt, ldsA + ldst[i]);
      gload_lds16(bgp[i] + kt, ldsB + ldst[i]);
    }
    __syncthreads();   // drains vmcnt before any wave reads the tiles
#pragma unroll
    for (int kk = 0; kk < 2; ++kk) {
      const int kb = kk * 64 + ((l >> 4) << 4);   // byte offset of K-octet
      f16x8 af[4], bfr[4];
#pragma unroll
      for (int mf = 0; mf < 4; ++mf) {
        const int r = (wm << 6) + (mf << 4) + (l & 15);
        af[mf] = *(const f16x8*)(ldsA + r * 128 + (kb ^ ((r & 7) << 4)));
      }
#pragma unroll
      for (int nf = 0; nf < 4; ++nf) {
        const int r = (wn << 6) + (nf << 4) + (l & 15);
        bfr[nf] = *(const f16x8*)(ldsB + r * 128 + (kb ^ ((r & 7) << 4)));
      }
#pragma unroll
      for (int mf = 0; mf < 4; ++mf)
#pragma unroll
        for (int nf = 0; nf < 4; ++nf)
          acc[mf][nf] = __builtin_amdgcn_mfma_f32_16x16x32_f16(
              af[mf], bfr[nf], acc[mf][nf], 0, 0, 0);
    }
    __syncthreads();
  }

  // epilogue: C/D layout col = lane&15, row = (lane>>4)*4 + j  (m89-verified)
  const int cr = (l >> 4) << 2;
  const int cc = l & 15;
#pragma unroll
  for (int mf = 0; mf < 4; ++mf) {
    const size_t rowb = m0 + (wm << 6) + (mf << 4) + cr;
    if constexpr (SCALED) {
      const int e = (int)(n0 >> 7);   // BN=128 == one expert's rank block
      float cs[4];
#pragma unroll
      for (int j = 0; j < 4; ++j) cs[j] = combine[(rowb + j) * 8 + e];
      _Float16* Y = (_Float16*)Cout;
#pragma unroll
      for (int nf = 0; nf < 4; ++nf) {
        const size_t col = n0 + (wn << 6) + (nf << 4) + cc;
#pragma unroll
        for (int j = 0; j < 4; ++j)
          Y[(rowb + j) * (size_t)ldc + col] = (_Float16)(acc[mf][nf][j] * cs[j]);
      }
    } else {
      float* O = (float*)Cout;
#pragma unroll
      for (int nf = 0; nf < 4; ++nf) {
        const size_t col = n0 + (wn << 6) + (nf << 4) + cc;
#pragma unroll
        for (int j = 0; j < 4; ++j)
          O[(rowb + j) * (size_t)ldc + col] = acc[mf][nf][j];
      }
    }
  }
}

// ------------------------------------------------------------------ launch
extern "C" void kernel_launch(void* const* d_in, const int* in_sizes, int n_in,
                              void* d_out, int out_size, void* d_ws, size_t ws_size,
                              hipStream_t stream) {
  const float* x  = (const float*)d_in[0];   // [4,4096,2048]
  const float* rw = (const float*)d_in[1];   // [2048,8]
  const float* Wa = (const float*)d_in[2];   // [8,2048,128]
  const float* Wb = (const float*)d_in[3];   // [8,128,2048]
  float* out = (float*)d_out;                // [4,4096,2048]

  char* ws = (char*)d_ws;
  // workspace layout (total 109,576,192 B)
  _Float16* xh      = (_Float16*)(ws);                 // 67,108,864  f16 x
  _Float16* WaT     = (_Float16*)(ws + 67108864);      //  4,194,304  [1024][2048]
  _Float16* WbT     = (_Float16*)(ws + 71303168);      //  4,194,304  [2048][1024]
  float*    combine = (float*)   (ws + 75497472);      //    524,288  [T][8]
  _Float16* Y       = (_Float16*)(ws + 76021760);      // 33,554,432  [T][1024]

  // WaT[(e*128+r)][k] = Wa[e][k][r]
  transpose_cast_f16<<<dim3(4, 64, 8), dim3(32, 8), 0, stream>>>(
      Wa, WaT, 2048, 128, 2048, (long)128 * 2048);
  // WbT[n][e*128+r] = Wb[e][r][n]
  transpose_cast_f16<<<dim3(64, 4, 8), dim3(32, 8), 0, stream>>>(
      Wb, WbT, 128, 2048, 1024, 128);

  router_kernel<<<TOKENS / 16, 256, 0, stream>>>(x, rw, combine, xh);

  // Y[t][e*128+r] = combine[t][e] * sum_k xh[t][k] * WaT[e*128+r][k]
  gemm_bt<DIM, true><<<dim3(NEXP * RANK / 128, TOKENS / 128), 256, 0, stream>>>(
      xh, WaT, combine, (void*)Y, NEXP * RANK);
  // out[t][o] = sum_n Y[t][n] * WbT[o][n]
  gemm_bt<NEXP * RANK, false><<<dim3(NOUT / 128, TOKENS / 128), 256, 0, stream>>>(
      Y, WbT, nullptr, (void*)out, NOUT);
}

// Round 2
// 319.227 us; speedup vs baseline: 1.1104x; 1.1104x over previous
//
#include <hip/hip_runtime.h>
#include <cstdint>
#include <cstddef>

#define TOKENS 16384
#define DIM    2048
#define NEXP   8
#define RANK   128
#define NOUT   2048

typedef __attribute__((ext_vector_type(4))) float    f32x4;
typedef __attribute__((ext_vector_type(8))) _Float16 f16x8;
typedef __attribute__((ext_vector_type(4))) _Float16 f16x4;

// ---------------------------------------------------------------- utilities
__device__ __forceinline__ void gload_lds16(const void* g, void* l) {
  __builtin_amdgcn_global_load_lds(
      (const __attribute__((address_space(1))) void*)g,
      (__attribute__((address_space(3))) void*)l, 16, 0, 0);
}

// ------------------------------------------------- transpose + cast to f16
// in: [E][R][C] fp32.  out element: out[e*obase + c*ostride + r] = in[e][r][c]
__global__ __launch_bounds__(256) void transpose_cast_f16(
    const float* __restrict__ in, _Float16* __restrict__ out,
    int R, int C, long ostride, long obase)
{
  __shared__ float tile[32][33];
  const int e = blockIdx.z;
  const float* ine = in + (size_t)e * R * C;
  const int c0 = blockIdx.x * 32, r0 = blockIdx.y * 32;
  const int tx = threadIdx.x, ty = threadIdx.y;
#pragma unroll
  for (int j = 0; j < 32; j += 8)
    tile[ty + j][tx] = ine[(size_t)(r0 + ty + j) * C + (c0 + tx)];
  __syncthreads();
#pragma unroll
  for (int j = 0; j < 32; j += 8)
    out[(size_t)e * obase + (size_t)(c0 + ty + j) * ostride + (r0 + tx)] =
        (_Float16)tile[tx][ty + j];
}

// ------------------------------------------------------------------ router
// ONE TOKEN PER WAVE (coalesced). Lane l handles elements c + 4*l; the wave's
// float4 load spans 1024 contiguous bytes. Full 64-lane shfl_xor reduction.
// Produces combine[T][8] (normalized top-2 softmax weights, zeros elsewhere)
// and xh = f16(x).
__global__ __launch_bounds__(256) void router_kernel(
    const float* __restrict__ x, const float* __restrict__ rw,
    float* __restrict__ combine, _Float16* __restrict__ xh)
{
  const int tid = threadIdx.x;
  const int wv = tid >> 6;
  const int l  = tid & 63;
  const size_t t = (size_t)blockIdx.x * 4 + wv;
  const float* xr  = x  + t * DIM;
  _Float16*    xhr = xh + t * DIM;

  float ss = 0.f;
  float lg[8];
#pragma unroll
  for (int e = 0; e < 8; ++e) lg[e] = 0.f;

#pragma unroll
  for (int c = 0; c < DIM; c += 256) {
    const int k0 = c + l * 4;
    float4 v = *(const float4*)(xr + k0);
    f16x4 hv;
    hv.x = (_Float16)v.x; hv.y = (_Float16)v.y;
    hv.z = (_Float16)v.z; hv.w = (_Float16)v.w;
    *(f16x4*)(xhr + k0) = hv;
    const float* rp = rw + (size_t)k0 * 8;
    float xs[4] = {v.x, v.y, v.z, v.w};
#pragma unroll
    for (int j = 0; j < 4; ++j) {
      const float xv = xs[j];
      ss = fmaf(xv, xv, ss);
      float4 r0 = *(const float4*)(rp + j * 8);
      float4 r1 = *(const float4*)(rp + j * 8 + 4);
      lg[0] = fmaf(xv, r0.x, lg[0]); lg[1] = fmaf(xv, r0.y, lg[1]);
      lg[2] = fmaf(xv, r0.z, lg[2]); lg[3] = fmaf(xv, r0.w, lg[3]);
      lg[4] = fmaf(xv, r1.x, lg[4]); lg[5] = fmaf(xv, r1.y, lg[5]);
      lg[6] = fmaf(xv, r1.z, lg[6]); lg[7] = fmaf(xv, r1.w, lg[7]);
    }
  }
  // reduce across all 64 lanes of this wave (one token)
#pragma unroll
  for (int m = 1; m < 64; m <<= 1) {
    ss += __shfl_xor(ss, m, 64);
#pragma unroll
    for (int e = 0; e < 8; ++e) lg[e] += __shfl_xor(lg[e], m, 64);
  }
  if (l == 0) {
    const float inv = 1.f / fmaxf(sqrtf(ss), 1e-12f);
#pragma unroll
    for (int e = 0; e < 8; ++e) lg[e] *= inv;
    // top-2 (static register indexing only)
    float b1 = lg[0]; int e1 = 0;
#pragma unroll
    for (int e = 1; e < 8; ++e)
      if (lg[e] > b1) { b1 = lg[e]; e1 = e; }
    float b2 = -3.4e38f; int e2 = 0;
#pragma unroll
    for (int e = 0; e < 8; ++e)
      if (e != e1 && lg[e] > b2) { b2 = lg[e]; e2 = e; }
    const float p2 = expf(b2 - b1);          // softmax top-2, renormalized
    const float w1 = 1.f / (1.f + p2);
    const float w2 = p2 * w1;
    float ov[8];
#pragma unroll
    for (int e = 0; e < 8; ++e)
      ov[e] = (e == e1) ? w1 : ((e == e2) ? w2 : 0.f);
    float4* cp = (float4*)(combine + t * 8);
    cp[0] = make_float4(ov[0], ov[1], ov[2], ov[3]);
    cp[1] = make_float4(ov[4], ov[5], ov[6], ov[7]);
  }
}

// -------------------------------------------------------------------- GEMM
// C[M][ldc] = A[M][KDIM] @ Bt[N][KDIM]^T, 128x128 tile, BK=64, 4 waves.
// global_load_lds(16B) with pre-swizzled source; XOR-swizzled ds_read_b128;
// 16x16x32 f16 MFMA. SCALED: C is f16, scaled by combine[row*8 + n0>>7].
template <int KDIM, bool SCALED>
__global__ __launch_bounds__(256) void gemm_bt(
    const _Float16* __restrict__ A, const _Float16* __restrict__ Bt,
    const float* __restrict__ combine, void* __restrict__ Cout, int ldc)
{
  __shared__ __align__(16) char lds[32768];
  char* ldsA = lds;
  char* ldsB = lds + 16384;
  const int tid = threadIdx.x;
  const int w = tid >> 6, l = tid & 63;
  const int wm = w >> 1, wn = w & 1;
  const size_t m0 = (size_t)blockIdx.y * 128;
  const size_t n0 = (size_t)blockIdx.x * 128;

  // staging: linear LDS dest, inverse-swizzled global source (rule #21)
  const int Lb = w * 1024 + l * 16;
  const _Float16* agp[4];
  const _Float16* bgp[4];
  int ldst[4];
#pragma unroll
  for (int i = 0; i < 4; ++i) {
    const int L = i * 4096 + Lb;
    const int row = L >> 7;                       // tile row (128B rows)
    const int cb = (L & 127) ^ ((row & 7) << 4);  // swizzled column byte
    agp[i] = A  + (m0 + row) * KDIM + (cb >> 1);
    bgp[i] = Bt + (n0 + row) * KDIM + (cb >> 1);
    ldst[i] = i * 4096 + w * 1024;                // wave-uniform LDS base
  }

  f32x4 acc[4][4];
#pragma unroll
  for (int a = 0; a < 4; ++a)
#pragma unroll
    for (int b = 0; b < 4; ++b)
#pragma unroll
      for (int j = 0; j < 4; ++j) acc[a][b][j] = 0.f;

  for (int kt = 0; kt < KDIM; kt += 64) {
#pragma unroll
    for (int i = 0; i < 4; ++i) {
      gload_lds16(agp[i] + kt, ldsA + ldst[i]);
      gload_lds16(bgp[i] + kt, ldsB + ldst[i]);
    }
    __syncthreads();   // drains vmcnt before any wave reads the tiles
#pragma unroll
    for (int kk = 0; kk < 2; ++kk) {
      const int kb = kk * 64 + ((l >> 4) << 4);   // byte offset of K-octet
      f16x8 af[4], bfr[4];
#pragma unroll
      for (int mf = 0; mf < 4; ++mf) {
        const int r = (wm << 6) + (mf << 4) + (l & 15);
        af[mf] = *(const f16x8*)(ldsA + r * 128 + (kb ^ ((r & 7) << 4)));
      }
#pragma unroll
      for (int nf = 0; nf < 4; ++nf) {
        const int r = (wn << 6) + (nf << 4) + (l & 15);
        bfr[nf] = *(const f16x8*)(ldsB + r * 128 + (kb ^ ((r & 7) << 4)));
      }
#pragma unroll
      for (int mf = 0; mf < 4; ++mf)
#pragma unroll
        for (int nf = 0; nf < 4; ++nf)
          acc[mf][nf] = __builtin_amdgcn_mfma_f32_16x16x32_f16(
              af[mf], bfr[nf], acc[mf][nf], 0, 0, 0);
    }
    __syncthreads();
  }

  // epilogue: C/D layout col = lane&15, row = (lane>>4)*4 + j  (m89-verified)
  const int cr = (l >> 4) << 2;
  const int cc = l & 15;
#pragma unroll
  for (int mf = 0; mf < 4; ++mf) {
    const size_t rowb = m0 + (wm << 6) + (mf << 4) + cr;
    if constexpr (SCALED) {
      const int e = (int)(n0 >> 7);   // BN=128 == one expert's rank block
      float cs[4];
#pragma unroll
      for (int j = 0; j < 4; ++j) cs[j] = combine[(rowb + j) * 8 + e];
      _Float16* Y = (_Float16*)Cout;
#pragma unroll
      for (int nf = 0; nf < 4; ++nf) {
        const size_t col = n0 + (wn << 6) + (nf << 4) + cc;
#pragma unroll
        for (int j = 0; j < 4; ++j)
          Y[(rowb + j) * (size_t)ldc + col] = (_Float16)(acc[mf][nf][j] * cs[j]);
      }
    } else {
      float* O = (float*)Cout;
#pragma unroll
      for (int nf = 0; nf < 4; ++nf) {
        const size_t col = n0 + (wn << 6) + (nf << 4) + cc;
#pragma unroll
        for (int j = 0; j < 4; ++j)
          O[(rowb + j) * (size_t)ldc + col] = acc[mf][nf][j];
      }
    }
  }
}

// ------------------------------------------------------------------ launch
extern "C" void kernel_launch(void* const* d_in, const int* in_sizes, int n_in,
                              void* d_out, int out_size, void* d_ws, size_t ws_size,
                              hipStream_t stream) {
  const float* x  = (const float*)d_in[0];   // [4,4096,2048]
  const float* rw = (const float*)d_in[1];   // [2048,8]
  const float* Wa = (const float*)d_in[2];   // [8,2048,128]
  const float* Wb = (const float*)d_in[3];   // [8,128,2048]
  float* out = (float*)d_out;                // [4,4096,2048]

  char* ws = (char*)d_ws;
  // workspace layout (total 109,576,192 B)
  _Float16* xh      = (_Float16*)(ws);                 // 67,108,864  f16 x
  _Float16* WaT     = (_Float16*)(ws + 67108864);      //  4,194,304  [1024][2048]
  _Float16* WbT     = (_Float16*)(ws + 71303168);      //  4,194,304  [2048][1024]
  float*    combine = (float*)   (ws + 75497472);      //    524,288  [T][8]
  _Float16* Y       = (_Float16*)(ws + 76021760);      // 33,554,432  [T][1024]

  // WaT[(e*128+r)][k] = Wa[e][k][r]
  transpose_cast_f16<<<dim3(4, 64, 8), dim3(32, 8), 0, stream>>>(
      Wa, WaT, 2048, 128, 2048, (long)128 * 2048);
  // WbT[n][e*128+r] = Wb[e][r][n]
  transpose_cast_f16<<<dim3(64, 4, 8), dim3(32, 8), 0, stream>>>(
      Wb, WbT, 128, 2048, 1024, 128);

  router_kernel<<<TOKENS / 4, 256, 0, stream>>>(x, rw, combine, xh);

  // Y[t][e*128+r] = combine[t][e] * sum_k xh[t][k] * WaT[e*128+r][k]
  gemm_bt<DIM, true><<<dim3(NEXP * RANK / 128, TOKENS / 128), 256, 0, stream>>>(
      xh, WaT, combine, (void*)Y, NEXP * RANK);
  // out[t][o] = sum_n Y[t][n] * WbT[o][n]
  gemm_bt<NEXP * RANK, false><<<dim3(NOUT / 128, TOKENS / 128), 256, 0, stream>>>(
      Y, WbT, nullptr, (void*)out, NOUT);
}

// Round 3
// 286.821 us; speedup vs baseline: 1.2358x; 1.1130x over previous
//
#include <hip/hip_runtime.h>
#include <cstdint>
#include <cstddef>

#define TOKENS 16384
#define DIM    2048
#define NEXP   8
#define RANK   128
#define NOUT   2048

typedef __attribute__((ext_vector_type(4))) float    f32x4;
typedef __attribute__((ext_vector_type(8))) _Float16 f16x8;
typedef __attribute__((ext_vector_type(4))) _Float16 f16x4;

// ---------------------------------------------------------------- utilities
__device__ __forceinline__ void gload_lds16(const void* g, void* l) {
  __builtin_amdgcn_global_load_lds(
      (const __attribute__((address_space(1))) void*)g,
      (__attribute__((address_space(3))) void*)l, 16, 0, 0);
}

// ------------------------------------------------- transpose + cast to f16
// in: [E][R][C] fp32.  out element: out[e*obase + c*ostride + r] = in[e][r][c]
__global__ __launch_bounds__(256) void transpose_cast_f16(
    const float* __restrict__ in, _Float16* __restrict__ out,
    int R, int C, long ostride, long obase)
{
  __shared__ float tile[32][33];
  const int e = blockIdx.z;
  const float* ine = in + (size_t)e * R * C;
  const int c0 = blockIdx.x * 32, r0 = blockIdx.y * 32;
  const int tx = threadIdx.x, ty = threadIdx.y;
#pragma unroll
  for (int j = 0; j < 32; j += 8)
    tile[ty + j][tx] = ine[(size_t)(r0 + ty + j) * C + (c0 + tx)];
  __syncthreads();
#pragma unroll
  for (int j = 0; j < 32; j += 8)
    out[(size_t)e * obase + (size_t)(c0 + ty + j) * ostride + (r0 + tx)] =
        (_Float16)tile[tx][ty + j];
}

// ------------------------------------------------------------------ router
// 16 tokens per block, 16 lanes per token. Lane p of a token group owns
// k in {64*u + 4*p}: at each u the 16 lanes read 16 CONSECUTIVE float4s
// (256B contiguous -> coalesced), and the wave's 4 token groups read the
// SAME rw cache lines (dedup/broadcast). 4-step shfl_xor 16-lane reduce.
// Produces combine[T][8] and xh = f16(x).
__global__ __launch_bounds__(256) void router_kernel(
    const float* __restrict__ x, const float* __restrict__ rw,
    float* __restrict__ combine, _Float16* __restrict__ xh)
{
  const int tid = threadIdx.x;
  const int tok = tid >> 4;
  const int fs  = tid & 15;
  const size_t t = (size_t)blockIdx.x * 16 + tok;
  const float*  xr  = x  + t * DIM;
  _Float16*     xhr = xh + t * DIM;

  float ss = 0.f;
  float lg[8];
#pragma unroll
  for (int e = 0; e < 8; ++e) lg[e] = 0.f;

#pragma unroll 2
  for (int u = 0; u < DIM / 64; ++u) {
    const int k0 = u * 64 + fs * 4;
    float4 v = *(const float4*)(xr + k0);
    f16x4 hv;
    hv.x = (_Float16)v.x; hv.y = (_Float16)v.y;
    hv.z = (_Float16)v.z; hv.w = (_Float16)v.w;
    *(f16x4*)(xhr + k0) = hv;
    const float* rp = rw + (size_t)k0 * 8;
    float xs[4] = {v.x, v.y, v.z, v.w};
#pragma unroll
    for (int j = 0; j < 4; ++j) {
      const float xv = xs[j];
      ss = fmaf(xv, xv, ss);
      float4 r0 = *(const float4*)(rp + j * 8);
      float4 r1 = *(const float4*)(rp + j * 8 + 4);
      lg[0] = fmaf(xv, r0.x, lg[0]); lg[1] = fmaf(xv, r0.y, lg[1]);
      lg[2] = fmaf(xv, r0.z, lg[2]); lg[3] = fmaf(xv, r0.w, lg[3]);
      lg[4] = fmaf(xv, r1.x, lg[4]); lg[5] = fmaf(xv, r1.y, lg[5]);
      lg[6] = fmaf(xv, r1.z, lg[6]); lg[7] = fmaf(xv, r1.w, lg[7]);
    }
  }
  // reduce across the 16 lanes of this token group
#pragma unroll
  for (int m = 1; m < 16; m <<= 1) {
    ss += __shfl_xor(ss, m, 64);
#pragma unroll
    for (int e = 0; e < 8; ++e) lg[e] += __shfl_xor(lg[e], m, 64);
  }
  if (fs == 0) {
    const float inv = 1.f / fmaxf(sqrtf(ss), 1e-12f);
#pragma unroll
    for (int e = 0; e < 8; ++e) lg[e] *= inv;
    // top-2 (static register indexing only)
    float b1 = lg[0]; int e1 = 0;
#pragma unroll
    for (int e = 1; e < 8; ++e)
      if (lg[e] > b1) { b1 = lg[e]; e1 = e; }
    float b2 = -3.4e38f; int e2 = 0;
#pragma unroll
    for (int e = 0; e < 8; ++e)
      if (e != e1 && lg[e] > b2) { b2 = lg[e]; e2 = e; }
    const float p2 = expf(b2 - b1);          // softmax top-2, renormalized
    const float w1 = 1.f / (1.f + p2);
    const float w2 = p2 * w1;
    float ov[8];
#pragma unroll
    for (int e = 0; e < 8; ++e)
      ov[e] = (e == e1) ? w1 : ((e == e2) ? w2 : 0.f);
    float4* cp = (float4*)(combine + t * 8);
    cp[0] = make_float4(ov[0], ov[1], ov[2], ov[3]);
    cp[1] = make_float4(ov[4], ov[5], ov[6], ov[7]);
  }
}

// -------------------------------------------------------------------- GEMM
// C[M][ldc] = A[M][KDIM] @ Bt[N][KDIM]^T, 128x128 tile, BK=64, 4 waves.
// global_load_lds(16B) with pre-swizzled source; XOR-swizzled ds_read_b128;
// 16x16x32 f16 MFMA. XCD-aware bijective block swizzle (T1; nwg % 8 == 0).
// SCALED: C is f16, scaled by combine[row*8 + n0>>7].
template <int KDIM, bool SCALED>
__global__ __launch_bounds__(256) void gemm_bt(
    const _Float16* __restrict__ A, const _Float16* __restrict__ Bt,
    const float* __restrict__ combine, void* __restrict__ Cout, int ldc)
{
  __shared__ __align__(16) char lds[32768];
  char* ldsA = lds;
  char* ldsB = lds + 16384;
  const int tid = threadIdx.x;
  const int w = tid >> 6, l = tid & 63;
  const int wm = w >> 1, wn = w & 1;

  // T1: XCD-aware swizzle of the linear block id (8 XCDs, round-robin HW map)
  const int nbx = gridDim.x;
  const int nwg = nbx * gridDim.y;
  int lid = blockIdx.y * nbx + blockIdx.x;
  lid = (lid & 7) * (nwg >> 3) + (lid >> 3);
  const size_t m0 = (size_t)(lid / nbx) * 128;
  const size_t n0 = (size_t)(lid % nbx) * 128;

  // staging: linear LDS dest, inverse-swizzled global source (rule #21)
  const int Lb = w * 1024 + l * 16;
  const _Float16* agp[4];
  const _Float16* bgp[4];
  int ldst[4];
#pragma unroll
  for (int i = 0; i < 4; ++i) {
    const int L = i * 4096 + Lb;
    const int row = L >> 7;                       // tile row (128B rows)
    const int cb = (L & 127) ^ ((row & 7) << 4);  // swizzled column byte
    agp[i] = A  + (m0 + row) * KDIM + (cb >> 1);
    bgp[i] = Bt + (n0 + row) * KDIM + (cb >> 1);
    ldst[i] = i * 4096 + w * 1024;                // wave-uniform LDS base
  }

  f32x4 acc[4][4];
#pragma unroll
  for (int a = 0; a < 4; ++a)
#pragma unroll
    for (int b = 0; b < 4; ++b)
#pragma unroll
      for (int j = 0; j < 4; ++j) acc[a][b][j] = 0.f;

  for (int kt = 0; kt < KDIM; kt += 64) {
#pragma unroll
    for (int i = 0; i < 4; ++i) {
      gload_lds16(agp[i] + kt, ldsA + ldst[i]);
      gload_lds16(bgp[i] + kt, ldsB + ldst[i]);
    }
    __syncthreads();   // drains vmcnt before any wave reads the tiles
#pragma unroll
    for (int kk = 0; kk < 2; ++kk) {
      const int kb = kk * 64 + ((l >> 4) << 4);   // byte offset of K-octet
      f16x8 af[4], bfr[4];
#pragma unroll
      for (int mf = 0; mf < 4; ++mf) {
        const int r = (wm << 6) + (mf << 4) + (l & 15);
        af[mf] = *(const f16x8*)(ldsA + r * 128 + (kb ^ ((r & 7) << 4)));
      }
#pragma unroll
      for (int nf = 0; nf < 4; ++nf) {
        const int r = (wn << 6) + (nf << 4) + (l & 15);
        bfr[nf] = *(const f16x8*)(ldsB + r * 128 + (kb ^ ((r & 7) << 4)));
      }
#pragma unroll
      for (int mf = 0; mf < 4; ++mf)
#pragma unroll
        for (int nf = 0; nf < 4; ++nf)
          acc[mf][nf] = __builtin_amdgcn_mfma_f32_16x16x32_f16(
              af[mf], bfr[nf], acc[mf][nf], 0, 0, 0);
    }
    __syncthreads();
  }

  // epilogue: C/D layout col = lane&15, row = (lane>>4)*4 + j  (m89-verified)
  const int cr = (l >> 4) << 2;
  const int cc = l & 15;
#pragma unroll
  for (int mf = 0; mf < 4; ++mf) {
    const size_t rowb = m0 + (wm << 6) + (mf << 4) + cr;
    if constexpr (SCALED) {
      const int e = (int)(n0 >> 7);   // BN=128 == one expert's rank block
      float cs[4];
#pragma unroll
      for (int j = 0; j < 4; ++j) cs[j] = combine[(rowb + j) * 8 + e];
      _Float16* Y = (_Float16*)Cout;
#pragma unroll
      for (int nf = 0; nf < 4; ++nf) {
        const size_t col = n0 + (wn << 6) + (nf << 4) + cc;
#pragma unroll
        for (int j = 0; j < 4; ++j)
          Y[(rowb + j) * (size_t)ldc + col] = (_Float16)(acc[mf][nf][j] * cs[j]);
      }
    } else {
      float* O = (float*)Cout;
#pragma unroll
      for (int nf = 0; nf < 4; ++nf) {
        const size_t col = n0 + (wn << 6) + (nf << 4) + cc;
#pragma unroll
        for (int j = 0; j < 4; ++j)
          O[(rowb + j) * (size_t)ldc + col] = acc[mf][nf][j];
      }
    }
  }
}

// ------------------------------------------------------------------ launch
extern "C" void kernel_launch(void* const* d_in, const int* in_sizes, int n_in,
                              void* d_out, int out_size, void* d_ws, size_t ws_size,
                              hipStream_t stream) {
  const float* x  = (const float*)d_in[0];   // [4,4096,2048]
  const float* rw = (const float*)d_in[1];   // [2048,8]
  const float* Wa = (const float*)d_in[2];   // [8,2048,128]
  const float* Wb = (const float*)d_in[3];   // [8,128,2048]
  float* out = (float*)d_out;                // [4,4096,2048]

  char* ws = (char*)d_ws;
  // workspace layout (total 109,576,192 B)
  _Float16* xh      = (_Float16*)(ws);                 // 67,108,864  f16 x
  _Float16* WaT     = (_Float16*)(ws + 67108864);      //  4,194,304  [1024][2048]
  _Float16* WbT     = (_Float16*)(ws + 71303168);      //  4,194,304  [2048][1024]
  float*    combine = (float*)   (ws + 75497472);      //    524,288  [T][8]
  _Float16* Y       = (_Float16*)(ws + 76021760);      // 33,554,432  [T][1024]

  // WaT[(e*128+r)][k] = Wa[e][k][r]
  transpose_cast_f16<<<dim3(4, 64, 8), dim3(32, 8), 0, stream>>>(
      Wa, WaT, 2048, 128, 2048, (long)128 * 2048);
  // WbT[n][e*128+r] = Wb[e][r][n]
  transpose_cast_f16<<<dim3(64, 4, 8), dim3(32, 8), 0, stream>>>(
      Wb, WbT, 128, 2048, 1024, 128);

  router_kernel<<<TOKENS / 16, 256, 0, stream>>>(x, rw, combine, xh);

  // Y[t][e*128+r] = combine[t][e] * sum_k xh[t][k] * WaT[e*128+r][k]
  gemm_bt<DIM, true><<<dim3(NEXP * RANK / 128, TOKENS / 128), 256, 0, stream>>>(
      xh, WaT, combine, (void*)Y, NEXP * RANK);
  // out[t][o] = sum_n Y[t][n] * WbT[o][n]
  gemm_bt<NEXP * RANK, false><<<dim3(NOUT / 128, TOKENS / 128), 256, 0, stream>>>(
      Y, WbT, nullptr, (void*)out, NOUT);
}

// Round 5
// 255.691 us; speedup vs baseline: 1.3863x; 1.1217x over previous
//
#include <hip/hip_runtime.h>
#include <cstdint>
#include <cstddef>

#define TOKENS 16384
#define DIM    2048
#define NEXP   8
#define RANK   128
#define NOUT   2048

typedef __attribute__((ext_vector_type(4))) float    f32x4;
typedef __attribute__((ext_vector_type(8))) _Float16 f16x8;
typedef __attribute__((ext_vector_type(4))) _Float16 f16x4;

// ---------------------------------------------------------------- utilities
__device__ __forceinline__ void gload_lds16(const void* g, void* l) {
  __builtin_amdgcn_global_load_lds(
      (const __attribute__((address_space(1))) void*)g,
      (__attribute__((address_space(3))) void*)l, 16, 0, 0);
}

// ------------------------------------------------- transpose + cast to f16
// in: [E][R][C] fp32.  out element: out[e*obase + c*ostride + r] = in[e][r][c]
__global__ __launch_bounds__(256) void transpose_cast_f16(
    const float* __restrict__ in, _Float16* __restrict__ out,
    int R, int C, long ostride, long obase)
{
  __shared__ float tile[32][33];
  const int e = blockIdx.z;
  const float* ine = in + (size_t)e * R * C;
  const int c0 = blockIdx.x * 32, r0 = blockIdx.y * 32;
  const int tx = threadIdx.x, ty = threadIdx.y;
#pragma unroll
  for (int j = 0; j < 32; j += 8)
    tile[ty + j][tx] = ine[(size_t)(r0 + ty + j) * C + (c0 + tx)];
  __syncthreads();
#pragma unroll
  for (int j = 0; j < 32; j += 8)
    out[(size_t)e * obase + (size_t)(c0 + ty + j) * ostride + (r0 + tx)] =
        (_Float16)tile[tx][ty + j];
}

// ----------------------------------------------------------------- cast_ss
// Pure streaming: xh = f16(x), inv[t] = 1/max(||x_t||,1e-12).
// 16 tokens/block, 16 lanes/token, k = u*64 + fs*4 (256B contiguous/group).
__global__ __launch_bounds__(256) void cast_ss_kernel(
    const float* __restrict__ x, float* __restrict__ inv,
    _Float16* __restrict__ xh)
{
  const int tid = threadIdx.x;
  const int tok = tid >> 4;
  const int fs  = tid & 15;
  const size_t t = (size_t)blockIdx.x * 16 + tok;
  const float* xr  = x  + t * DIM;
  _Float16*    xhr = xh + t * DIM;

  float ss = 0.f;
#pragma unroll 4
  for (int u = 0; u < DIM / 64; ++u) {
    const int k0 = u * 64 + fs * 4;
    float4 v = *(const float4*)(xr + k0);
    f16x4 hv;
    hv.x = (_Float16)v.x; hv.y = (_Float16)v.y;
    hv.z = (_Float16)v.z; hv.w = (_Float16)v.w;
    *(f16x4*)(xhr + k0) = hv;
    ss = fmaf(v.x, v.x, fmaf(v.y, v.y, fmaf(v.z, v.z, fmaf(v.w, v.w, ss))));
  }
#pragma unroll
  for (int m = 1; m < 16; m <<= 1) ss += __shfl_xor(ss, m, 64);
  if (fs == 0) inv[t] = 1.f / fmaxf(sqrtf(ss), 1e-12f);
}

// ------------------------------------------------------------- logits_part
// lgpart[ks][t][e] = sum_{k in slice ks} x[t][k] * rw[k][e]  (fp32-accurate)
// via double-f16 split MFMA: x = ah+ae, rw = bh+be;
//   x*rw ~= ah*bh + ah*be + ae*bh   (dropped ae*be ~ 2^-22 rel).
// Block: 128 tokens x 512-wide K slice, 4 waves (32 token-rows each).
// A: fp32 x tile staged via gload_lds into XOR-swizzled 256B-row LDS,
//    converted to (ah,ae) f16 fragments in-register.
// B: rw slice split-cast into two swizzled f16 tiles (rows 8..15 zero).
__global__ __launch_bounds__(256) void logits_part_kernel(
    const float* __restrict__ x, const float* __restrict__ rw,
    float* __restrict__ lgpart)
{
  __shared__ __align__(16) char lds[65536];
  char* ldsA  = lds;           // [128 rows][256B fp32], swizzled
  char* ldsBh = lds + 32768;   // [16][1024B f16] hi
  char* ldsBe = lds + 49152;   // [16][1024B f16] lo
  const int tid = threadIdx.x;
  const int w = tid >> 6, l = tid & 63;
  const int m0 = blockIdx.x * 128;
  const int ks = blockIdx.y;            // K-slice, 512 wide
  const int kbase = ks * 512;

  // split-cast rw slice -> (ldsBh, ldsBe), byte ^= ((n&7)<<4); rows 8..15 = 0
#pragma unroll
  for (int i = 0; i < 32; ++i) {
    const int idx = tid * 32 + i;       // 0..8191 over [16][512]
    const int n = idx >> 9, k = idx & 511;
    const float v = (n < 8) ? rw[(size_t)(kbase + k) * 8 + n] : 0.f;
    const _Float16 h = (_Float16)v;
    const _Float16 e = (_Float16)(v - (float)h);
    const int off = n * 1024 + ((k * 2) ^ ((n & 7) << 4));
    *(_Float16*)(ldsBh + off) = h;
    *(_Float16*)(ldsBe + off) = e;
  }

  // A staging: fp32 rows of 256B; linear LDS dest, inverse-swizzled source
  const int Lb = w * 1024 + l * 16;
  const float* agp[8];
  int ldst[8];
#pragma unroll
  for (int i = 0; i < 8; ++i) {
    const int L = i * 4096 + Lb;
    const int row = L >> 8;                       // 256B fp32 rows
    const int cb = (L & 255) ^ ((row & 7) << 4);  // swizzled column byte
    agp[i] = x + (size_t)(m0 + row) * DIM + kbase + (cb >> 2);
    ldst[i] = i * 4096 + w * 1024;                // wave-uniform LDS base
  }

  f32x4 acc[2];
#pragma unroll
  for (int mf = 0; mf < 2; ++mf)
#pragma unroll
    for (int j = 0; j < 4; ++j) acc[mf][j] = 0.f;

  for (int st = 0; st < 8; ++st) {
#pragma unroll
    for (int i = 0; i < 8; ++i)
      gload_lds16(agp[i] + st * 64, ldsA + ldst[i]);
    __syncthreads();                     // covers B writes on st==0 too
#pragma unroll
    for (int kk = 0; kk < 2; ++kk) {
      const int n = l & 15;
      const int bko = n * 1024 +
          ((st * 128 + kk * 64 + ((l >> 4) << 4)) ^ ((n & 7) << 4));
      const f16x8 bh = *(const f16x8*)(ldsBh + bko);
      const f16x8 be = *(const f16x8*)(ldsBe + bko);
#pragma unroll
      for (int mf = 0; mf < 2; ++mf) {
        const int r = w * 32 + mf * 16 + (l & 15);
        const int s = (r & 7) << 4;
        const int c0 = kk * 128 + ((l >> 4) << 5);   // 32B-aligned col byte
        const f32x4 va = *(const f32x4*)(ldsA + r * 256 + ((c0) ^ s));
        const f32x4 vb = *(const f32x4*)(ldsA + r * 256 + ((c0 + 16) ^ s));
        float f[8] = {va[0], va[1], va[2], va[3], vb[0], vb[1], vb[2], vb[3]};
        f16x8 ah, ae;
#pragma unroll
        for (int j = 0; j < 8; ++j) {
          ah[j] = (_Float16)f[j];
          ae[j] = (_Float16)(f[j] - (float)ah[j]);
        }
        acc[mf] = __builtin_amdgcn_mfma_f32_16x16x32_f16(ae, bh, acc[mf], 0, 0, 0);
        acc[mf] = __builtin_amdgcn_mfma_f32_16x16x32_f16(ah, be, acc[mf], 0, 0, 0);
        acc[mf] = __builtin_amdgcn_mfma_f32_16x16x32_f16(ah, bh, acc[mf], 0, 0, 0);
      }
    }
    __syncthreads();
  }

  // C/D layout: col = lane&15, row = (lane>>4)*4 + j
  const int col = l & 15;
  if (col < 8) {
#pragma unroll
    for (int mf = 0; mf < 2; ++mf) {
      const int rbase = m0 + w * 32 + mf * 16 + ((l >> 4) << 2);
#pragma unroll
      for (int j = 0; j < 4; ++j)
        lgpart[((size_t)ks * TOKENS + rbase + j) * 8 + col] = acc[mf][j];
    }
  }
}

// ------------------------------------------------------------ softmax_top2
// combine[t][e]: sum 4 K-slice partials, scale by inv[t], top-2 softmax.
__global__ __launch_bounds__(256) void softmax_top2_kernel(
    const float* __restrict__ lgpart, const float* __restrict__ inv,
    float* __restrict__ combine)
{
  const size_t t = (size_t)blockIdx.x * 256 + threadIdx.x;
  const float iv = inv[t];
  float lg[8];
#pragma unroll
  for (int e = 0; e < 8; ++e) lg[e] = 0.f;
#pragma unroll
  for (int ks = 0; ks < 4; ++ks) {
    const float* p = lgpart + ((size_t)ks * TOKENS + t) * 8;
    float4 a = *(const float4*)(p);
    float4 b = *(const float4*)(p + 4);
    lg[0] += a.x; lg[1] += a.y; lg[2] += a.z; lg[3] += a.w;
    lg[4] += b.x; lg[5] += b.y; lg[6] += b.z; lg[7] += b.w;
  }
#pragma unroll
  for (int e = 0; e < 8; ++e) lg[e] *= iv;
  float b1 = lg[0]; int e1 = 0;
#pragma unroll
  for (int e = 1; e < 8; ++e)
    if (lg[e] > b1) { b1 = lg[e]; e1 = e; }
  float b2 = -3.4e38f; int e2 = 0;
#pragma unroll
  for (int e = 0; e < 8; ++e)
    if (e != e1 && lg[e] > b2) { b2 = lg[e]; e2 = e; }
  const float p2 = expf(b2 - b1);
  const float w1 = 1.f / (1.f + p2);
  const float w2 = p2 * w1;
  float ov[8];
#pragma unroll
  for (int e = 0; e < 8; ++e)
    ov[e] = (e == e1) ? w1 : ((e == e2) ? w2 : 0.f);
  float4* cp = (float4*)(combine + t * 8);
  cp[0] = make_float4(ov[0], ov[1], ov[2], ov[3]);
  cp[1] = make_float4(ov[4], ov[5], ov[6], ov[7]);
}

// -------------------------------------------------------------------- GEMM
// C[M][ldc] = A[M][KDIM] @ Bt[N][KDIM]^T, 128x128 tile, BK=64, 4 waves.
// global_load_lds(16B) with pre-swizzled source; XOR-swizzled ds_read_b128;
// 16x16x32 f16 MFMA. XCD-aware bijective block swizzle (T1; nwg % 8 == 0).
// SCALED: C is f16, scaled by combine[row*8 + n0>>7].
template <int KDIM, bool SCALED>
__global__ __launch_bounds__(256) void gemm_bt(
    const _Float16* __restrict__ A, const _Float16* __restrict__ Bt,
    const float* __restrict__ combine, void* __restrict__ Cout, int ldc)
{
  __shared__ __align__(16) char lds[32768];
  char* ldsA = lds;
  char* ldsB = lds + 16384;
  const int tid = threadIdx.x;
  const int w = tid >> 6, l = tid & 63;
  const int wm = w >> 1, wn = w & 1;

  // T1: XCD-aware swizzle of the linear block id (8 XCDs, round-robin HW map)
  const int nbx = gridDim.x;
  const int nwg = nbx * gridDim.y;
  int lid = blockIdx.y * nbx + blockIdx.x;
  lid = (lid & 7) * (nwg >> 3) + (lid >> 3);
  const size_t m0 = (size_t)(lid / nbx) * 128;
  const size_t n0 = (size_t)(lid % nbx) * 128;

  // staging: linear LDS dest, inverse-swizzled global source (rule #21)
  const int Lb = w * 1024 + l * 16;
  const _Float16* agp[4];
  const _Float16* bgp[4];
  int ldst[4];
#pragma unroll
  for (int i = 0; i < 4; ++i) {
    const int L = i * 4096 + Lb;
    const int row = L >> 7;                       // tile row (128B rows)
    const int cb = (L & 127) ^ ((row & 7) << 4);  // swizzled column byte
    agp[i] = A  + (m0 + row) * KDIM + (cb >> 1);
    bgp[i] = Bt + (n0 + row) * KDIM + (cb >> 1);
    ldst[i] = i * 4096 + w * 1024;                // wave-uniform LDS base
  }

  f32x4 acc[4][4];
#pragma unroll
  for (int a = 0; a < 4; ++a)
#pragma unroll
    for (int b = 0; b < 4; ++b)
#pragma unroll
      for (int j = 0; j < 4; ++j) acc[a][b][j] = 0.f;

  for (int kt = 0; kt < KDIM; kt += 64) {
#pragma unroll
    for (int i = 0; i < 4; ++i) {
      gload_lds16(agp[i] + kt, ldsA + ldst[i]);
      gload_lds16(bgp[i] + kt, ldsB + ldst[i]);
    }
    __syncthreads();   // drains vmcnt before any wave reads the tiles
#pragma unroll
    for (int kk = 0; kk < 2; ++kk) {
      const int kb = kk * 64 + ((l >> 4) << 4);   // byte offset of K-octet
      f16x8 af[4], bfr[4];
#pragma unroll
      for (int mf = 0; mf < 4; ++mf) {
        const int r = (wm << 6) + (mf << 4) + (l & 15);
        af[mf] = *(const f16x8*)(ldsA + r * 128 + (kb ^ ((r & 7) << 4)));
      }
#pragma unroll
      for (int nf = 0; nf < 4; ++nf) {
        const int r = (wn << 6) + (nf << 4) + (l & 15);
        bfr[nf] = *(const f16x8*)(ldsB + r * 128 + (kb ^ ((r & 7) << 4)));
      }
#pragma unroll
      for (int mf = 0; mf < 4; ++mf)
#pragma unroll
        for (int nf = 0; nf < 4; ++nf)
          acc[mf][nf] = __builtin_amdgcn_mfma_f32_16x16x32_f16(
              af[mf], bfr[nf], acc[mf][nf], 0, 0, 0);
    }
    __syncthreads();
  }

  // epilogue: C/D layout col = lane&15, row = (lane>>4)*4 + j  (m89-verified)
  const int cr = (l >> 4) << 2;
  const int cc = l & 15;
#pragma unroll
  for (int mf = 0; mf < 4; ++mf) {
    const size_t rowb = m0 + (wm << 6) + (mf << 4) + cr;
    if constexpr (SCALED) {
      const int e = (int)(n0 >> 7);   // BN=128 == one expert's rank block
      float cs[4];
#pragma unroll
      for (int j = 0; j < 4; ++j) cs[j] = combine[(rowb + j) * 8 + e];
      _Float16* Y = (_Float16*)Cout;
#pragma unroll
      for (int nf = 0; nf < 4; ++nf) {
        const size_t col = n0 + (wn << 6) + (nf << 4) + cc;
#pragma unroll
        for (int j = 0; j < 4; ++j)
          Y[(rowb + j) * (size_t)ldc + col] = (_Float16)(acc[mf][nf][j] * cs[j]);
      }
    } else {
      float* O = (float*)Cout;
#pragma unroll
      for (int nf = 0; nf < 4; ++nf) {
        const size_t col = n0 + (wn << 6) + (nf << 4) + cc;
#pragma unroll
        for (int j = 0; j < 4; ++j)
          O[(rowb + j) * (size_t)ldc + col] = acc[mf][nf][j];
      }
    }
  }
}

// ------------------------------------------------------------------ launch
extern "C" void kernel_launch(void* const* d_in, const int* in_sizes, int n_in,
                              void* d_out, int out_size, void* d_ws, size_t ws_size,
                              hipStream_t stream) {
  const float* x  = (const float*)d_in[0];   // [4,4096,2048]
  const float* rw = (const float*)d_in[1];   // [2048,8]
  const float* Wa = (const float*)d_in[2];   // [8,2048,128]
  const float* Wb = (const float*)d_in[3];   // [8,128,2048]
  float* out = (float*)d_out;                // [4,4096,2048]

  char* ws = (char*)d_ws;
  // workspace layout (total 109,641,728 B)
  _Float16* xh      = (_Float16*)(ws);                 // 67,108,864  f16 x
  _Float16* WaT     = (_Float16*)(ws + 67108864);      //  4,194,304  [1024][2048]
  _Float16* WbT     = (_Float16*)(ws + 71303168);      //  4,194,304  [2048][1024]
  float*    combine = (float*)   (ws + 75497472);      //    524,288  [T][8]
  float*    inv     = (float*)   (ws + 76021760);      //     65,536  [T]
  _Float16* Y       = (_Float16*)(ws + 76087296);      // 33,554,432  [T][1024]
  float*    lgpart  = (float*)   (ws + 76087296);      // aliases Y: consumed
                                                       // by softmax before
                                                       // gemm1 writes Y

  // WaT[(e*128+r)][k] = Wa[e][k][r]
  transpose_cast_f16<<<dim3(4, 64, 8), dim3(32, 8), 0, stream>>>(
      Wa, WaT, 2048, 128, 2048, (long)128 * 2048);
  // WbT[n][e*128+r] = Wb[e][r][n]
  transpose_cast_f16<<<dim3(64, 4, 8), dim3(32, 8), 0, stream>>>(
      Wb, WbT, 128, 2048, 1024, 128);

  cast_ss_kernel<<<TOKENS / 16, 256, 0, stream>>>(x, inv, xh);
  logits_part_kernel<<<dim3(TOKENS / 128, 4), 256, 0, stream>>>(x, rw, lgpart);
  softmax_top2_kernel<<<TOKENS / 256, 256, 0, stream>>>(lgpart, inv, combine);

  // Y[t][e*128+r] = combine[t][e] * sum_k xh[t][k] * WaT[e*128+r][k]
  gemm_bt<DIM, true><<<dim3(NEXP * RANK / 128, TOKENS / 128), 256, 0, stream>>>(
      xh, WaT, combine, (void*)Y, NEXP * RANK);
  // out[t][o] = sum_n Y[t][n] * WbT[o][n]
  gemm_bt<NEXP * RANK, false><<<dim3(NOUT / 128, TOKENS / 128), 256, 0, stream>>>(
      Y, WbT, nullptr, (void*)out, NOUT);
}

// Round 6
// 246.752 us; speedup vs baseline: 1.4365x; 1.0362x over previous
//
#include <hip/hip_runtime.h>
#include <cstdint>
#include <cstddef>

#define TOKENS 16384
#define DIM    2048
#define NEXP   8
#define RANK   128
#define NOUT   2048
#define CAP    8192   // per-pair-bin token capacity (avg ~585, 14x headroom)

typedef __attribute__((ext_vector_type(4))) float    f32x4;
typedef __attribute__((ext_vector_type(8))) _Float16 f16x8;
typedef __attribute__((ext_vector_type(4))) _Float16 f16x4;

// ---------------------------------------------------------------- utilities
__device__ __forceinline__ void gload_lds16(const void* g, void* l) {
  __builtin_amdgcn_global_load_lds(
      (const __attribute__((address_space(1))) void*)g,
      (__attribute__((address_space(3))) void*)l, 16, 0, 0);
}

// ------------------------------------------------- transpose + cast to f16
// in: [E][R][C] fp32.  out element: out[e*obase + c*ostride + r] = in[e][r][c]
__global__ __launch_bounds__(256) void transpose_cast_f16(
    const float* __restrict__ in, _Float16* __restrict__ out,
    int R, int C, long ostride, long obase)
{
  __shared__ float tile[32][33];
  const int e = blockIdx.z;
  const float* ine = in + (size_t)e * R * C;
  const int c0 = blockIdx.x * 32, r0 = blockIdx.y * 32;
  const int tx = threadIdx.x, ty = threadIdx.y;
#pragma unroll
  for (int j = 0; j < 32; j += 8)
    tile[ty + j][tx] = ine[(size_t)(r0 + ty + j) * C + (c0 + tx)];
  __syncthreads();
#pragma unroll
  for (int j = 0; j < 32; j += 8)
    out[(size_t)e * obase + (size_t)(c0 + ty + j) * ostride + (r0 + tx)] =
        (_Float16)tile[tx][ty + j];
}

// ----------------------------------------------------------------- cast_ss
// Pure streaming: xh = f16(x), inv[t] = 1/max(||x_t||,1e-12).
__global__ __launch_bounds__(256) void cast_ss_kernel(
    const float* __restrict__ x, float* __restrict__ inv,
    _Float16* __restrict__ xh)
{
  const int tid = threadIdx.x;
  const int tok = tid >> 4;
  const int fs  = tid & 15;
  const size_t t = (size_t)blockIdx.x * 16 + tok;
  const float* xr  = x  + t * DIM;
  _Float16*    xhr = xh + t * DIM;

  float ss = 0.f;
#pragma unroll 4
  for (int u = 0; u < DIM / 64; ++u) {
    const int k0 = u * 64 + fs * 4;
    float4 v = *(const float4*)(xr + k0);
    f16x4 hv;
    hv.x = (_Float16)v.x; hv.y = (_Float16)v.y;
    hv.z = (_Float16)v.z; hv.w = (_Float16)v.w;
    *(f16x4*)(xhr + k0) = hv;
    ss = fmaf(v.x, v.x, fmaf(v.y, v.y, fmaf(v.z, v.z, fmaf(v.w, v.w, ss))));
  }
#pragma unroll
  for (int m = 1; m < 16; m <<= 1) ss += __shfl_xor(ss, m, 64);
  if (fs == 0) inv[t] = 1.f / fmaxf(sqrtf(ss), 1e-12f);
}

// ------------------------------------------------------------- logits_part
// lgpart[ks][t][e] = sum_{k in slice ks} x[t][k] * rw[k][e]  (fp32-accurate)
// via double-f16 split MFMA (x=ah+ae, rw=bh+be; drop ae*be ~2^-22).
__global__ __launch_bounds__(256) void logits_part_kernel(
    const float* __restrict__ x, const float* __restrict__ rw,
    float* __restrict__ lgpart)
{
  __shared__ __align__(16) char lds[65536];
  char* ldsA  = lds;           // [128 rows][256B fp32], swizzled
  char* ldsBh = lds + 32768;   // [16][1024B f16] hi
  char* ldsBe = lds + 49152;   // [16][1024B f16] lo
  const int tid = threadIdx.x;
  const int w = tid >> 6, l = tid & 63;
  const int m0 = blockIdx.x * 128;
  const int ks = blockIdx.y;            // K-slice, 512 wide
  const int kbase = ks * 512;

#pragma unroll
  for (int i = 0; i < 32; ++i) {
    const int idx = tid * 32 + i;       // 0..8191 over [16][512]
    const int n = idx >> 9, k = idx & 511;
    const float v = (n < 8) ? rw[(size_t)(kbase + k) * 8 + n] : 0.f;
    const _Float16 h = (_Float16)v;
    const _Float16 e = (_Float16)(v - (float)h);
    const int off = n * 1024 + ((k * 2) ^ ((n & 7) << 4));
    *(_Float16*)(ldsBh + off) = h;
    *(_Float16*)(ldsBe + off) = e;
  }

  const int Lb = w * 1024 + l * 16;
  const float* agp[8];
  int ldst[8];
#pragma unroll
  for (int i = 0; i < 8; ++i) {
    const int L = i * 4096 + Lb;
    const int row = L >> 8;                       // 256B fp32 rows
    const int cb = (L & 255) ^ ((row & 7) << 4);
    agp[i] = x + (size_t)(m0 + row) * DIM + kbase + (cb >> 2);
    ldst[i] = i * 4096 + w * 1024;
  }

  f32x4 acc[2];
#pragma unroll
  for (int mf = 0; mf < 2; ++mf)
#pragma unroll
    for (int j = 0; j < 4; ++j) acc[mf][j] = 0.f;

  for (int st = 0; st < 8; ++st) {
#pragma unroll
    for (int i = 0; i < 8; ++i)
      gload_lds16(agp[i] + st * 64, ldsA + ldst[i]);
    __syncthreads();
#pragma unroll
    for (int kk = 0; kk < 2; ++kk) {
      const int n = l & 15;
      const int bko = n * 1024 +
          ((st * 128 + kk * 64 + ((l >> 4) << 4)) ^ ((n & 7) << 4));
      const f16x8 bh = *(const f16x8*)(ldsBh + bko);
      const f16x8 be = *(const f16x8*)(ldsBe + bko);
#pragma unroll
      for (int mf = 0; mf < 2; ++mf) {
        const int r = w * 32 + mf * 16 + (l & 15);
        const int s = (r & 7) << 4;
        const int c0 = kk * 128 + ((l >> 4) << 5);
        const f32x4 va = *(const f32x4*)(ldsA + r * 256 + ((c0) ^ s));
        const f32x4 vb = *(const f32x4*)(ldsA + r * 256 + ((c0 + 16) ^ s));
        float f[8] = {va[0], va[1], va[2], va[3], vb[0], vb[1], vb[2], vb[3]};
        f16x8 ah, ae;
#pragma unroll
        for (int j = 0; j < 8; ++j) {
          ah[j] = (_Float16)f[j];
          ae[j] = (_Float16)(f[j] - (float)ah[j]);
        }
        acc[mf] = __builtin_amdgcn_mfma_f32_16x16x32_f16(ae, bh, acc[mf], 0, 0, 0);
        acc[mf] = __builtin_amdgcn_mfma_f32_16x16x32_f16(ah, be, acc[mf], 0, 0, 0);
        acc[mf] = __builtin_amdgcn_mfma_f32_16x16x32_f16(ah, bh, acc[mf], 0, 0, 0);
      }
    }
    __syncthreads();
  }

  const int col = l & 15;
  if (col < 8) {
#pragma unroll
    for (int mf = 0; mf < 2; ++mf) {
      const int rbase = m0 + w * 32 + mf * 16 + ((l >> 4) << 2);
#pragma unroll
      for (int j = 0; j < 4; ++j)
        lgpart[((size_t)ks * TOKENS + rbase + j) * 8 + col] = acc[mf][j];
    }
  }
}

// ------------------------------------------------------------ softmax_top2
// combine[t][e]; pairinfo[t] = a | (b<<8) (a<b selected experts);
// bins token t into pair bin a*8+b (ids16). Bin order is nondeterministic
// (atomicAdd) but per-token output is order-independent -> deterministic.
__global__ __launch_bounds__(256) void softmax_top2_kernel(
    const float* __restrict__ lgpart, const float* __restrict__ inv,
    float* __restrict__ combine, int* __restrict__ pairinfo,
    int* __restrict__ counts, unsigned short* __restrict__ ids16)
{
  const size_t t = (size_t)blockIdx.x * 256 + threadIdx.x;
  const float iv = inv[t];
  float lg[8];
#pragma unroll
  for (int e = 0; e < 8; ++e) lg[e] = 0.f;
#pragma unroll
  for (int ks = 0; ks < 4; ++ks) {
    const float* p = lgpart + ((size_t)ks * TOKENS + t) * 8;
    float4 a = *(const float4*)(p);
    float4 b = *(const float4*)(p + 4);
    lg[0] += a.x; lg[1] += a.y; lg[2] += a.z; lg[3] += a.w;
    lg[4] += b.x; lg[5] += b.y; lg[6] += b.z; lg[7] += b.w;
  }
#pragma unroll
  for (int e = 0; e < 8; ++e) lg[e] *= iv;
  float b1 = lg[0]; int e1 = 0;
#pragma unroll
  for (int e = 1; e < 8; ++e)
    if (lg[e] > b1) { b1 = lg[e]; e1 = e; }
  float b2 = -3.4e38f; int e2 = 0;
#pragma unroll
  for (int e = 0; e < 8; ++e)
    if (e != e1 && lg[e] > b2) { b2 = lg[e]; e2 = e; }
  const float p2 = expf(b2 - b1);
  const float w1 = 1.f / (1.f + p2);
  const float w2 = p2 * w1;
  float ov[8];
#pragma unroll
  for (int e = 0; e < 8; ++e)
    ov[e] = (e == e1) ? w1 : ((e == e2) ? w2 : 0.f);
  float4* cp = (float4*)(combine + t * 8);
  cp[0] = make_float4(ov[0], ov[1], ov[2], ov[3]);
  cp[1] = make_float4(ov[4], ov[5], ov[6], ov[7]);

  const int a = min(e1, e2), b = max(e1, e2);
  pairinfo[t] = a | (b << 8);
  const int bin = a * 8 + b;
  const int pos = atomicAdd(&counts[bin], 1);
  if (pos < CAP) ids16[bin * CAP + pos] = (unsigned short)t;
}

// -------------------------------------------------------------- make_items
// Compact M-tile work list for gemm2_pair. Total tiles <= 16384/128 + 64
// = 192 (provable). items[j] = {bin, ids-base, valid-rows, 0} or bin=-1.
__global__ void make_items_kernel(const int* __restrict__ counts,
                                  int4* __restrict__ items)
{
  if (threadIdx.x == 0 && blockIdx.x == 0) {
    int j = 0;
    for (int b = 0; b < 64; ++b) {
      int c = counts[b]; if (c > CAP) c = CAP;
      for (int s = 0; s < c; s += 128)
        items[j++] = make_int4(b, b * CAP + s, min(128, c - s), 0);
    }
    for (; j < 192; ++j) items[j] = make_int4(-1, 0, 0, 0);
  }
}

// ------------------------------------------------------------------- GEMM1
// Dense: for all 8 experts, Ytile = xh @ WaT_e^T; epilogue stores ONLY the
// two selected slices per token, scaled, into compact Y[t][256]
// (slot0 = lower expert index a, slot1 = b). 128x128 tile, BK=64, 4 waves.
__global__ __launch_bounds__(256) void gemm1_kernel(
    const _Float16* __restrict__ A, const _Float16* __restrict__ Bt,
    const float* __restrict__ combine, const int* __restrict__ pairinfo,
    _Float16* __restrict__ Yc)
{
  __shared__ __align__(16) char lds[32768];
  char* ldsA = lds;
  char* ldsB = lds + 16384;
  const int tid = threadIdx.x;
  const int w = tid >> 6, l = tid & 63;
  const int wm = w >> 1, wn = w & 1;

  // T1: XCD-aware bijective block swizzle (nwg = 1024, %8 == 0)
  const int nbx = gridDim.x;
  const int nwg = nbx * gridDim.y;
  int lid = blockIdx.y * nbx + blockIdx.x;
  lid = (lid & 7) * (nwg >> 3) + (lid >> 3);
  const size_t m0 = (size_t)(lid / nbx) * 128;
  const size_t n0 = (size_t)(lid % nbx) * 128;

  const int Lb = w * 1024 + l * 16;
  const _Float16* agp[4];
  const _Float16* bgp[4];
  int ldst[4];
#pragma unroll
  for (int i = 0; i < 4; ++i) {
    const int L = i * 4096 + Lb;
    const int row = L >> 7;
    const int cb = (L & 127) ^ ((row & 7) << 4);
    agp[i] = A  + (m0 + row) * DIM + (cb >> 1);
    bgp[i] = Bt + (n0 + row) * DIM + (cb >> 1);
    ldst[i] = i * 4096 + w * 1024;
  }

  f32x4 acc[4][4];
#pragma unroll
  for (int a = 0; a < 4; ++a)
#pragma unroll
    for (int b = 0; b < 4; ++b)
#pragma unroll
      for (int j = 0; j < 4; ++j) acc[a][b][j] = 0.f;

  for (int kt = 0; kt < DIM; kt += 64) {
#pragma unroll
    for (int i = 0; i < 4; ++i) {
      gload_lds16(agp[i] + kt, ldsA + ldst[i]);
      gload_lds16(bgp[i] + kt, ldsB + ldst[i]);
    }
    __syncthreads();
#pragma unroll
    for (int kk = 0; kk < 2; ++kk) {
      const int kb = kk * 64 + ((l >> 4) << 4);
      f16x8 af[4], bfr[4];
#pragma unroll
      for (int mf = 0; mf < 4; ++mf) {
        const int r = (wm << 6) + (mf << 4) + (l & 15);
        af[mf] = *(const f16x8*)(ldsA + r * 128 + (kb ^ ((r & 7) << 4)));
      }
#pragma unroll
      for (int nf = 0; nf < 4; ++nf) {
        const int r = (wn << 6) + (nf << 4) + (l & 15);
        bfr[nf] = *(const f16x8*)(ldsB + r * 128 + (kb ^ ((r & 7) << 4)));
      }
#pragma unroll
      for (int mf = 0; mf < 4; ++mf)
#pragma unroll
        for (int nf = 0; nf < 4; ++nf)
          acc[mf][nf] = __builtin_amdgcn_mfma_f32_16x16x32_f16(
              af[mf], bfr[nf], acc[mf][nf], 0, 0, 0);
    }
    __syncthreads();
  }

  // epilogue: C/D layout col = lane&15, row = (lane>>4)*4 + j
  const int cr = (l >> 4) << 2;
  const int cc = l & 15;
  const int e = (int)(n0 >> 7);
#pragma unroll
  for (int mf = 0; mf < 4; ++mf) {
    const size_t rowb = m0 + (wm << 6) + (mf << 4) + cr;
#pragma unroll
    for (int j = 0; j < 4; ++j) {
      const size_t t = rowb + j;
      const int info = pairinfo[t];
      const int slot = (e == (info & 255)) ? 0 : (e == (info >> 8)) ? 1 : -1;
      if (slot >= 0) {
        const float cs = combine[t * 8 + e];
        _Float16* yr = Yc + t * 256 + slot * 128;
#pragma unroll
        for (int nf = 0; nf < 4; ++nf)
          yr[(wn << 6) + (nf << 4) + cc] = (_Float16)(acc[mf][nf][j] * cs);
      }
    }
  }
}

// -------------------------------------------------------------- gemm2_pair
// Grouped by expert pair: out[t] = Y[t][0:256] @ [Wb_a; Wb_b] for tokens in
// this tile's pair bin. K=256 (4 BK=64 steps), A rows gathered by token id,
// epilogue scatters each token's out row exactly once (no atomics/RMW).
__global__ __launch_bounds__(256) void gemm2_pair_kernel(
    const _Float16* __restrict__ Y, const _Float16* __restrict__ WbT,
    const unsigned short* __restrict__ ids, const int4* __restrict__ items,
    float* __restrict__ out)
{
  __shared__ __align__(16) char lds[32768];
  __shared__ int ids_lds[128];
  char* ldsA = lds;
  char* ldsB = lds + 16384;
  const int4 item = items[blockIdx.y];
  if (item.x < 0) return;                 // block-uniform exit
  const int a = item.x >> 3, b = item.x & 7;
  const int n0 = blockIdx.x * 128;
  const int tid = threadIdx.x;
  const int w = tid >> 6, l = tid & 63;
  const int wm = w >> 1, wn = w & 1;

  if (tid < 128)
    ids_lds[tid] = (tid < item.z) ? (int)ids[item.y + tid] : -1;
  __syncthreads();

  const int Lb = w * 1024 + l * 16;
  const _Float16* aptr[4];
  const _Float16* bptrA[4];
  const _Float16* bptrB[4];
  int ldst[4];
#pragma unroll
  for (int i = 0; i < 4; ++i) {
    const int L = i * 4096 + Lb;
    const int row = L >> 7;
    const int cb = (L & 127) ^ ((row & 7) << 4);
    int t = ids_lds[row]; if (t < 0) t = 0;       // pad rows read token 0
    aptr[i]  = Y + (size_t)t * 256 + (cb >> 1);
    bptrA[i] = WbT + (size_t)(n0 + row) * 1024 + a * 128 + (cb >> 1);
    bptrB[i] = WbT + (size_t)(n0 + row) * 1024 + b * 128 + (cb >> 1);
    ldst[i] = i * 4096 + w * 1024;
  }

  f32x4 acc[4][4];
#pragma unroll
  for (int p = 0; p < 4; ++p)
#pragma unroll
    for (int q = 0; q < 4; ++q)
#pragma unroll
      for (int j = 0; j < 4; ++j) acc[p][q][j] = 0.f;

#pragma unroll
  for (int kt = 0; kt < 4; ++kt) {
#pragma unroll
    for (int i = 0; i < 4; ++i) {
      gload_lds16(aptr[i] + kt * 64, ldsA + ldst[i]);
      const _Float16* bs = (kt < 2) ? (bptrA[i] + kt * 64)
                                    : (bptrB[i] + (kt - 2) * 64);
      gload_lds16(bs, ldsB + ldst[i]);
    }
    __syncthreads();
#pragma unroll
    for (int kk = 0; kk < 2; ++kk) {
      const int kb = kk * 64 + ((l >> 4) << 4);
      f16x8 af[4], bfr[4];
#pragma unroll
      for (int mf = 0; mf < 4; ++mf) {
        const int r = (wm << 6) + (mf << 4) + (l & 15);
        af[mf] = *(const f16x8*)(ldsA + r * 128 + (kb ^ ((r & 7) << 4)));
      }
#pragma unroll
      for (int nf = 0; nf < 4; ++nf) {
        const int r = (wn << 6) + (nf << 4) + (l & 15);
        bfr[nf] = *(const f16x8*)(ldsB + r * 128 + (kb ^ ((r & 7) << 4)));
      }
#pragma unroll
      for (int mf = 0; mf < 4; ++mf)
#pragma unroll
        for (int nf = 0; nf < 4; ++nf)
          acc[mf][nf] = __builtin_amdgcn_mfma_f32_16x16x32_f16(
              af[mf], bfr[nf], acc[mf][nf], 0, 0, 0);
    }
    __syncthreads();
  }

  // epilogue: scatter rows to out[token]
  const int cr = (l >> 4) << 2;
  const int cc = l & 15;
#pragma unroll
  for (int mf = 0; mf < 4; ++mf) {
    const int lr0 = (wm << 6) + (mf << 4) + cr;
#pragma unroll
    for (int j = 0; j < 4; ++j) {
      const int t = ids_lds[lr0 + j];
      if (t < 0) continue;
      float* orow = out + (size_t)t * NOUT + n0;
#pragma unroll
      for (int nf = 0; nf < 4; ++nf)
        orow[(wn << 6) + (nf << 4) + cc] = acc[mf][nf][j];
    }
  }
}

// ------------------------------------------------------------------ launch
extern "C" void kernel_launch(void* const* d_in, const int* in_sizes, int n_in,
                              void* d_out, int out_size, void* d_ws, size_t ws_size,
                              hipStream_t stream) {
  const float* x  = (const float*)d_in[0];   // [4,4096,2048]
  const float* rw = (const float*)d_in[1];   // [2048,8]
  const float* Wa = (const float*)d_in[2];   // [8,2048,128]
  const float* Wb = (const float*)d_in[3];   // [8,128,2048]
  float* out = (float*)d_out;                // [4,4096,2048]

  char* ws = (char*)d_ws;
  // workspace layout (total ~85.6 MB)
  _Float16* xh       = (_Float16*)(ws);                // 67,108,864
  _Float16* WaT      = (_Float16*)(ws + 67108864);     //  4,194,304 [1024][2048]
  _Float16* WbT      = (_Float16*)(ws + 71303168);     //  4,194,304 [2048][1024]
  float*    combine  = (float*)   (ws + 75497472);     //    524,288 [T][8]
  float*    inv      = (float*)   (ws + 76021760);     //     65,536 [T]
  int*      pairinfo = (int*)     (ws + 76087296);     //     65,536 [T]
  int*      counts   = (int*)     (ws + 76152832);     //        256 [64]
  int4*     items    = (int4*)    (ws + 76153088);     //      3,072 [192]
  unsigned short* ids16 = (unsigned short*)(ws + 76156160); // 1,048,576 [64][CAP]
  _Float16* Yc       = (_Float16*)(ws + 77204736);     //  8,388,608 [T][256]
  float*    lgpart   = (float*)   (ws + 77204736);     // 2 MB, aliases Yc:
                                                       // consumed by softmax
                                                       // before gemm1 writes Yc

  // WaT[(e*128+r)][k] = Wa[e][k][r]
  transpose_cast_f16<<<dim3(4, 64, 8), dim3(32, 8), 0, stream>>>(
      Wa, WaT, 2048, 128, 2048, (long)128 * 2048);
  // WbT[n][e*128+r] = Wb[e][r][n]
  transpose_cast_f16<<<dim3(64, 4, 8), dim3(32, 8), 0, stream>>>(
      Wb, WbT, 128, 2048, 1024, 128);

  cast_ss_kernel<<<TOKENS / 16, 256, 0, stream>>>(x, inv, xh);
  logits_part_kernel<<<dim3(TOKENS / 128, 4), 256, 0, stream>>>(x, rw, lgpart);

  hipMemsetAsync(counts, 0, 64 * sizeof(int), stream);
  softmax_top2_kernel<<<TOKENS / 256, 256, 0, stream>>>(
      lgpart, inv, combine, pairinfo, counts, ids16);
  make_items_kernel<<<1, 64, 0, stream>>>(counts, items);

  // Yc[t][slot*128+r] = combine[t][e_slot] * (xh[t] . WaT[e_slot*128+r])
  gemm1_kernel<<<dim3(NEXP * RANK / 128, TOKENS / 128), 256, 0, stream>>>(
      xh, WaT, combine, pairinfo, Yc);
  // out[t] = Yc[t][0:256] @ [Wb_a; Wb_b]
  gemm2_pair_kernel<<<dim3(NOUT / 128, 192), 256, 0, stream>>>(
      Yc, WbT, ids16, items, out);
}

// Round 7
// 200.060 us; speedup vs baseline: 1.7718x; 1.2334x over previous
//
#include <hip/hip_runtime.h>
#include <cstdint>
#include <cstddef>

#define TOKENS 16384
#define DIM    2048
#define NEXP   8
#define RANK   128
#define NOUT   2048
#define CAP    8192   // per-pair-bin token capacity (avg ~585, 14x headroom)

typedef __attribute__((ext_vector_type(4))) float    f32x4;
typedef __attribute__((ext_vector_type(8))) _Float16 f16x8;
typedef __attribute__((ext_vector_type(4))) _Float16 f16x4;

// ---------------------------------------------------------------- utilities
__device__ __forceinline__ void gload_lds16(const void* g, void* l) {
  __builtin_amdgcn_global_load_lds(
      (const __attribute__((address_space(1))) void*)g,
      (__attribute__((address_space(3))) void*)l, 16, 0, 0);
}

// ------------------------------------------------- transpose + cast to f16
// in: [E][R][C] fp32.  out element: out[e*obase + c*ostride + r] = in[e][r][c]
__global__ __launch_bounds__(256) void transpose_cast_f16(
    const float* __restrict__ in, _Float16* __restrict__ out,
    int R, int C, long ostride, long obase)
{
  __shared__ float tile[32][33];
  const int e = blockIdx.z;
  const float* ine = in + (size_t)e * R * C;
  const int c0 = blockIdx.x * 32, r0 = blockIdx.y * 32;
  const int tx = threadIdx.x, ty = threadIdx.y;
#pragma unroll
  for (int j = 0; j < 32; j += 8)
    tile[ty + j][tx] = ine[(size_t)(r0 + ty + j) * C + (c0 + tx)];
  __syncthreads();
#pragma unroll
  for (int j = 0; j < 32; j += 8)
    out[(size_t)e * obase + (size_t)(c0 + ty + j) * ostride + (r0 + tx)] =
        (_Float16)tile[tx][ty + j];
}

// ------------------------------------------------------------ logits_fused
// Per (128-token, 512-K-slice) block:
//  - lgpart[ks][t][e] = x-slice . rw-slice   (double-f16 split MFMA, fp32 acc)
//  - xh = f16(x)  (stored from the already-computed 'ah' fragments)
//  - ssqpart[ks][t] = sum of x^2 over the slice (register + shfl reduce,
//    deterministic)
__global__ __launch_bounds__(256) void logits_fused_kernel(
    const float* __restrict__ x, const float* __restrict__ rw,
    float* __restrict__ lgpart, float* __restrict__ ssqpart,
    _Float16* __restrict__ xh)
{
  __shared__ __align__(16) char lds[65536];
  char* ldsA  = lds;           // [128 rows][256B fp32], swizzled
  char* ldsBh = lds + 32768;   // [16][1024B f16] hi
  char* ldsBe = lds + 49152;   // [16][1024B f16] lo
  const int tid = threadIdx.x;
  const int w = tid >> 6, l = tid & 63;
  const int m0 = blockIdx.x * 128;
  const int ks = blockIdx.y;            // K-slice, 512 wide
  const int kbase = ks * 512;

  // split-cast rw slice -> (ldsBh, ldsBe), byte ^= ((n&7)<<4); rows 8..15 = 0
#pragma unroll
  for (int i = 0; i < 32; ++i) {
    const int idx = tid * 32 + i;       // 0..8191 over [16][512]
    const int n = idx >> 9, k = idx & 511;
    const float v = (n < 8) ? rw[(size_t)(kbase + k) * 8 + n] : 0.f;
    const _Float16 h = (_Float16)v;
    const _Float16 e = (_Float16)(v - (float)h);
    const int off = n * 1024 + ((k * 2) ^ ((n & 7) << 4));
    *(_Float16*)(ldsBh + off) = h;
    *(_Float16*)(ldsBe + off) = e;
  }

  const int Lb = w * 1024 + l * 16;
  const float* agp[8];
  int ldst[8];
#pragma unroll
  for (int i = 0; i < 8; ++i) {
    const int L = i * 4096 + Lb;
    const int row = L >> 8;                       // 256B fp32 rows
    const int cb = (L & 255) ^ ((row & 7) << 4);
    agp[i] = x + (size_t)(m0 + row) * DIM + kbase + (cb >> 2);
    ldst[i] = i * 4096 + w * 1024;
  }

  f32x4 acc[2];
  float ssl[2] = {0.f, 0.f};
#pragma unroll
  for (int mf = 0; mf < 2; ++mf)
#pragma unroll
    for (int j = 0; j < 4; ++j) acc[mf][j] = 0.f;

  for (int st = 0; st < 8; ++st) {
#pragma unroll
    for (int i = 0; i < 8; ++i)
      gload_lds16(agp[i] + st * 64, ldsA + ldst[i]);
    __syncthreads();
#pragma unroll
    for (int kk = 0; kk < 2; ++kk) {
      const int n = l & 15;
      const int bko = n * 1024 +
          ((st * 128 + kk * 64 + ((l >> 4) << 4)) ^ ((n & 7) << 4));
      const f16x8 bh = *(const f16x8*)(ldsBh + bko);
      const f16x8 be = *(const f16x8*)(ldsBe + bko);
#pragma unroll
      for (int mf = 0; mf < 2; ++mf) {
        const int r = w * 32 + mf * 16 + (l & 15);
        const int s = (r & 7) << 4;
        const int c0 = kk * 128 + ((l >> 4) << 5);
        const f32x4 va = *(const f32x4*)(ldsA + r * 256 + ((c0) ^ s));
        const f32x4 vb = *(const f32x4*)(ldsA + r * 256 + ((c0 + 16) ^ s));
        float f[8] = {va[0], va[1], va[2], va[3], vb[0], vb[1], vb[2], vb[3]};
        f16x8 ah, ae;
#pragma unroll
        for (int j = 0; j < 8; ++j) {
          ah[j] = (_Float16)f[j];
          ae[j] = (_Float16)(f[j] - (float)ah[j]);
          ssl[mf] = fmaf(f[j], f[j], ssl[mf]);
        }
        // xh = f16(x): fragment covers 8 contiguous cols of row r
        *(f16x8*)(xh + (size_t)(m0 + r) * DIM + kbase + st * 64 + kk * 32 +
                  ((l >> 4) << 3)) = ah;
        acc[mf] = __builtin_amdgcn_mfma_f32_16x16x32_f16(ae, bh, acc[mf], 0, 0, 0);
        acc[mf] = __builtin_amdgcn_mfma_f32_16x16x32_f16(ah, be, acc[mf], 0, 0, 0);
        acc[mf] = __builtin_amdgcn_mfma_f32_16x16x32_f16(ah, bh, acc[mf], 0, 0, 0);
      }
    }
    __syncthreads();
  }

  // lgpart: C/D layout col = lane&15, row = (lane>>4)*4 + j
  const int col = l & 15;
  if (col < 8) {
#pragma unroll
    for (int mf = 0; mf < 2; ++mf) {
      const int rbase = m0 + w * 32 + mf * 16 + ((l >> 4) << 2);
#pragma unroll
      for (int j = 0; j < 4; ++j)
        lgpart[((size_t)ks * TOKENS + rbase + j) * 8 + col] = acc[mf][j];
    }
  }
  // ssqpart: each lane's ssl[mf] covers 128 cols of row w*32+mf*16+(l&15);
  // sum the 4 column-groups (lane bits 4,5), write from lanes l<16.
#pragma unroll
  for (int mf = 0; mf < 2; ++mf) {
    float s = ssl[mf];
    s += __shfl_xor(s, 16, 64);
    s += __shfl_xor(s, 32, 64);
    if (l < 16)
      ssqpart[(size_t)ks * TOKENS + m0 + w * 32 + mf * 16 + l] = s;
  }
}

// ------------------------------------------------------------ softmax_top2
// combine[t][e]; pairinfo[t] = a | (b<<8); bins token t into pair bin a*8+b.
// Bin order nondeterministic (atomicAdd) but per-token output values are
// order-independent.
__global__ __launch_bounds__(256) void softmax_top2_kernel(
    const float* __restrict__ lgpart, const float* __restrict__ ssqpart,
    float* __restrict__ combine, int* __restrict__ pairinfo,
    int* __restrict__ counts, unsigned short* __restrict__ ids16)
{
  const size_t t = (size_t)blockIdx.x * 256 + threadIdx.x;
  float ss = 0.f;
  float lg[8];
#pragma unroll
  for (int e = 0; e < 8; ++e) lg[e] = 0.f;
#pragma unroll
  for (int ks = 0; ks < 4; ++ks) {
    ss += ssqpart[(size_t)ks * TOKENS + t];
    const float* p = lgpart + ((size_t)ks * TOKENS + t) * 8;
    float4 a = *(const float4*)(p);
    float4 b = *(const float4*)(p + 4);
    lg[0] += a.x; lg[1] += a.y; lg[2] += a.z; lg[3] += a.w;
    lg[4] += b.x; lg[5] += b.y; lg[6] += b.z; lg[7] += b.w;
  }
  const float iv = 1.f / fmaxf(sqrtf(ss), 1e-12f);
#pragma unroll
  for (int e = 0; e < 8; ++e) lg[e] *= iv;
  float b1 = lg[0]; int e1 = 0;
#pragma unroll
  for (int e = 1; e < 8; ++e)
    if (lg[e] > b1) { b1 = lg[e]; e1 = e; }
  float b2 = -3.4e38f; int e2 = 0;
#pragma unroll
  for (int e = 0; e < 8; ++e)
    if (e != e1 && lg[e] > b2) { b2 = lg[e]; e2 = e; }
  const float p2 = expf(b2 - b1);
  const float w1 = 1.f / (1.f + p2);
  const float w2 = p2 * w1;
  float ov[8];
#pragma unroll
  for (int e = 0; e < 8; ++e)
    ov[e] = (e == e1) ? w1 : ((e == e2) ? w2 : 0.f);
  float4* cp = (float4*)(combine + t * 8);
  cp[0] = make_float4(ov[0], ov[1], ov[2], ov[3]);
  cp[1] = make_float4(ov[4], ov[5], ov[6], ov[7]);

  const int a = min(e1, e2), b = max(e1, e2);
  pairinfo[t] = a | (b << 8);
  const int bin = a * 8 + b;
  const int pos = atomicAdd(&counts[bin], 1);
  if (pos < CAP) ids16[bin * CAP + pos] = (unsigned short)t;
}

// -------------------------------------------------------------- make_items
// Compact M-tile work list. Total tiles <= 16384/128 + 64 = 192 (provable).
__global__ void make_items_kernel(const int* __restrict__ counts,
                                  int4* __restrict__ items)
{
  if (threadIdx.x == 0 && blockIdx.x == 0) {
    int j = 0;
    for (int b = 0; b < 64; ++b) {
      int c = counts[b]; if (c > CAP) c = CAP;
      for (int s = 0; s < c; s += 128)
        items[j++] = make_int4(b, b * CAP + s, min(128, c - s), 0);
    }
    for (; j < 192; ++j) items[j] = make_int4(-1, 0, 0, 0);
  }
}

// -------------------------------------------------------------- gemm1_pair
// Grouped by pair bin: for this tile's tokens, compute the slot-expert's
// Y slice:  Yc[t][slot*128+r] = combine[t][e] * (xh[t] . WaT[e*128+r]).
// K = 2048 (32 BK=64 steps), A rows gathered by token id.
__global__ __launch_bounds__(256) void gemm1_pair_kernel(
    const _Float16* __restrict__ xh, const _Float16* __restrict__ WaT,
    const float* __restrict__ combine, const unsigned short* __restrict__ ids,
    const int4* __restrict__ items, _Float16* __restrict__ Yc)
{
  __shared__ __align__(16) char lds[32768];
  __shared__ int ids_lds[128];
  char* ldsA = lds;
  char* ldsB = lds + 16384;
  const int4 item = items[blockIdx.y];
  if (item.x < 0) return;                 // block-uniform exit
  const int slot = blockIdx.x;
  const int e = slot ? (item.x & 7) : (item.x >> 3);
  const int tid = threadIdx.x;
  const int w = tid >> 6, l = tid & 63;
  const int wm = w >> 1, wn = w & 1;

  if (tid < 128)
    ids_lds[tid] = (tid < item.z) ? (int)ids[item.y + tid] : -1;
  __syncthreads();

  const int Lb = w * 1024 + l * 16;
  const _Float16* aptr[4];
  const _Float16* bptr[4];
  int ldst[4];
#pragma unroll
  for (int i = 0; i < 4; ++i) {
    const int L = i * 4096 + Lb;
    const int row = L >> 7;
    const int cb = (L & 127) ^ ((row & 7) << 4);
    int t = ids_lds[row]; if (t < 0) t = 0;       // pad rows read token 0
    aptr[i] = xh + (size_t)t * DIM + (cb >> 1);
    bptr[i] = WaT + (size_t)(e * 128 + row) * DIM + (cb >> 1);
    ldst[i] = i * 4096 + w * 1024;
  }

  f32x4 acc[4][4];
#pragma unroll
  for (int p = 0; p < 4; ++p)
#pragma unroll
    for (int q = 0; q < 4; ++q)
#pragma unroll
      for (int j = 0; j < 4; ++j) acc[p][q][j] = 0.f;

  for (int kt = 0; kt < DIM; kt += 64) {
#pragma unroll
    for (int i = 0; i < 4; ++i) {
      gload_lds16(aptr[i] + kt, ldsA + ldst[i]);
      gload_lds16(bptr[i] + kt, ldsB + ldst[i]);
    }
    __syncthreads();
#pragma unroll
    for (int kk = 0; kk < 2; ++kk) {
      const int kb = kk * 64 + ((l >> 4) << 4);
      f16x8 af[4], bfr[4];
#pragma unroll
      for (int mf = 0; mf < 4; ++mf) {
        const int r = (wm << 6) + (mf << 4) + (l & 15);
        af[mf] = *(const f16x8*)(ldsA + r * 128 + (kb ^ ((r & 7) << 4)));
      }
#pragma unroll
      for (int nf = 0; nf < 4; ++nf) {
        const int r = (wn << 6) + (nf << 4) + (l & 15);
        bfr[nf] = *(const f16x8*)(ldsB + r * 128 + (kb ^ ((r & 7) << 4)));
      }
#pragma unroll
      for (int mf = 0; mf < 4; ++mf)
#pragma unroll
        for (int nf = 0; nf < 4; ++nf)
          acc[mf][nf] = __builtin_amdgcn_mfma_f32_16x16x32_f16(
              af[mf], bfr[nf], acc[mf][nf], 0, 0, 0);
    }
    __syncthreads();
  }

  // epilogue: scale by combine[t][e], write compact Yc slot
  const int cr = (l >> 4) << 2;
  const int cc = l & 15;
#pragma unroll
  for (int mf = 0; mf < 4; ++mf) {
    const int lr0 = (wm << 6) + (mf << 4) + cr;
#pragma unroll
    for (int j = 0; j < 4; ++j) {
      const int t = ids_lds[lr0 + j];
      if (t < 0) continue;
      const float cs = combine[(size_t)t * 8 + e];
      _Float16* yr = Yc + (size_t)t * 256 + slot * 128;
#pragma unroll
      for (int nf = 0; nf < 4; ++nf)
        yr[(wn << 6) + (nf << 4) + cc] = (_Float16)(acc[mf][nf][j] * cs);
    }
  }
}

// -------------------------------------------------------------- gemm2_pair
// out[t] = Yc[t][0:256] @ [Wb_a; Wb_b] for tokens in this tile's pair bin.
__global__ __launch_bounds__(256) void gemm2_pair_kernel(
    const _Float16* __restrict__ Y, const _Float16* __restrict__ WbT,
    const unsigned short* __restrict__ ids, const int4* __restrict__ items,
    float* __restrict__ out)
{
  __shared__ __align__(16) char lds[32768];
  __shared__ int ids_lds[128];
  char* ldsA = lds;
  char* ldsB = lds + 16384;
  const int4 item = items[blockIdx.y];
  if (item.x < 0) return;                 // block-uniform exit
  const int a = item.x >> 3, b = item.x & 7;
  const int n0 = blockIdx.x * 128;
  const int tid = threadIdx.x;
  const int w = tid >> 6, l = tid & 63;
  const int wm = w >> 1, wn = w & 1;

  if (tid < 128)
    ids_lds[tid] = (tid < item.z) ? (int)ids[item.y + tid] : -1;
  __syncthreads();

  const int Lb = w * 1024 + l * 16;
  const _Float16* aptr[4];
  const _Float16* bptrA[4];
  const _Float16* bptrB[4];
  int ldst[4];
#pragma unroll
  for (int i = 0; i < 4; ++i) {
    const int L = i * 4096 + Lb;
    const int row = L >> 7;
    const int cb = (L & 127) ^ ((row & 7) << 4);
    int t = ids_lds[row]; if (t < 0) t = 0;       // pad rows read token 0
    aptr[i]  = Y + (size_t)t * 256 + (cb >> 1);
    bptrA[i] = WbT + (size_t)(n0 + row) * 1024 + a * 128 + (cb >> 1);
    bptrB[i] = WbT + (size_t)(n0 + row) * 1024 + b * 128 + (cb >> 1);
    ldst[i] = i * 4096 + w * 1024;
  }

  f32x4 acc[4][4];
#pragma unroll
  for (int p = 0; p < 4; ++p)
#pragma unroll
    for (int q = 0; q < 4; ++q)
#pragma unroll
      for (int j = 0; j < 4; ++j) acc[p][q][j] = 0.f;

#pragma unroll
  for (int kt = 0; kt < 4; ++kt) {
#pragma unroll
    for (int i = 0; i < 4; ++i) {
      gload_lds16(aptr[i] + kt * 64, ldsA + ldst[i]);
      const _Float16* bs = (kt < 2) ? (bptrA[i] + kt * 64)
                                    : (bptrB[i] + (kt - 2) * 64);
      gload_lds16(bs, ldsB + ldst[i]);
    }
    __syncthreads();
#pragma unroll
    for (int kk = 0; kk < 2; ++kk) {
      const int kb = kk * 64 + ((l >> 4) << 4);
      f16x8 af[4], bfr[4];
#pragma unroll
      for (int mf = 0; mf < 4; ++mf) {
        const int r = (wm << 6) + (mf << 4) + (l & 15);
        af[mf] = *(const f16x8*)(ldsA + r * 128 + (kb ^ ((r & 7) << 4)));
      }
#pragma unroll
      for (int nf = 0; nf < 4; ++nf) {
        const int r = (wn << 6) + (nf << 4) + (l & 15);
        bfr[nf] = *(const f16x8*)(ldsB + r * 128 + (kb ^ ((r & 7) << 4)));
      }
#pragma unroll
      for (int mf = 0; mf < 4; ++mf)
#pragma unroll
        for (int nf = 0; nf < 4; ++nf)
          acc[mf][nf] = __builtin_amdgcn_mfma_f32_16x16x32_f16(
              af[mf], bfr[nf], acc[mf][nf], 0, 0, 0);
    }
    __syncthreads();
  }

  // epilogue: scatter rows to out[token]
  const int cr = (l >> 4) << 2;
  const int cc = l & 15;
#pragma unroll
  for (int mf = 0; mf < 4; ++mf) {
    const int lr0 = (wm << 6) + (mf << 4) + cr;
#pragma unroll
    for (int j = 0; j < 4; ++j) {
      const int t = ids_lds[lr0 + j];
      if (t < 0) continue;
      float* orow = out + (size_t)t * NOUT + n0;
#pragma unroll
      for (int nf = 0; nf < 4; ++nf)
        orow[(wn << 6) + (nf << 4) + cc] = acc[mf][nf][j];
    }
  }
}

// ------------------------------------------------------------------ launch
extern "C" void kernel_launch(void* const* d_in, const int* in_sizes, int n_in,
                              void* d_out, int out_size, void* d_ws, size_t ws_size,
                              hipStream_t stream) {
  const float* x  = (const float*)d_in[0];   // [4,4096,2048]
  const float* rw = (const float*)d_in[1];   // [2048,8]
  const float* Wa = (const float*)d_in[2];   // [8,2048,128]
  const float* Wb = (const float*)d_in[3];   // [8,128,2048]
  float* out = (float*)d_out;                // [4,4096,2048]

  char* ws = (char*)d_ws;
  // workspace layout (total ~85.5 MB)
  _Float16* xh       = (_Float16*)(ws);                // 67,108,864 [T][2048]
  _Float16* WaT      = (_Float16*)(ws + 67108864);     //  4,194,304 [1024][2048]
  _Float16* WbT      = (_Float16*)(ws + 71303168);     //  4,194,304 [2048][1024]
  float*    combine  = (float*)   (ws + 75497472);     //    524,288 [T][8]
  int*      pairinfo = (int*)     (ws + 76021760);     //     65,536 [T]
  int*      counts   = (int*)     (ws + 76087296);     //        256 [64]
  int4*     items    = (int4*)    (ws + 76087552);     //      3,072 [192]
  unsigned short* ids16 = (unsigned short*)(ws + 76090624); // 1,048,576 [64][CAP]
  _Float16* Yc       = (_Float16*)(ws + 77139200);     //  8,388,608 [T][256]
  float*    lgpart   = (float*)   (ws + 77139200);     // 2 MB, aliases Yc
  float*    ssqpart  = (float*)   (ws + 79236352);     // 256 KB, aliases Yc
  // (lgpart/ssqpart consumed by softmax before gemm1_pair writes Yc)

  // WaT[(e*128+r)][k] = Wa[e][k][r]
  transpose_cast_f16<<<dim3(4, 64, 8), dim3(32, 8), 0, stream>>>(
      Wa, WaT, 2048, 128, 2048, (long)128 * 2048);
  // WbT[n][e*128+r] = Wb[e][r][n]
  transpose_cast_f16<<<dim3(64, 4, 8), dim3(32, 8), 0, stream>>>(
      Wb, WbT, 128, 2048, 1024, 128);

  logits_fused_kernel<<<dim3(TOKENS / 128, 4), 256, 0, stream>>>(
      x, rw, lgpart, ssqpart, xh);

  hipMemsetAsync(counts, 0, 64 * sizeof(int), stream);
  softmax_top2_kernel<<<TOKENS / 256, 256, 0, stream>>>(
      lgpart, ssqpart, combine, pairinfo, counts, ids16);
  make_items_kernel<<<1, 64, 0, stream>>>(counts, items);

  // Yc[t][slot*128+r] = combine[t][e_slot] * (xh[t] . WaT[e_slot*128+r])
  gemm1_pair_kernel<<<dim3(2, 192), 256, 0, stream>>>(
      xh, WaT, combine, ids16, items, Yc);
  // out[t] = Yc[t][0:256] @ [Wb_a; Wb_b]
  gemm2_pair_kernel<<<dim3(NOUT / 128, 192), 256, 0, stream>>>(
      Yc, WbT, ids16, items, out);
}